// Round 1
// baseline (637.884 us; speedup 1.0000x reference)
//
#include <hip/hip_runtime.h>

typedef unsigned short u16;
typedef __attribute__((ext_vector_type(8))) short s8v;   // 8 x bf16 (as shorts)
typedef __attribute__((ext_vector_type(4))) float f4v;

__device__ __forceinline__ u16 f2bf(float f){
  unsigned u = __float_as_uint(f);
  unsigned r = (u + 0x7FFFu + ((u >> 16) & 1u)) >> 16;
  return (u16)r;
}
__device__ __forceinline__ float bf2f(u16 h){
  return __uint_as_float(((unsigned)h) << 16);
}
__device__ __forceinline__ float sigmf(float x){
  return __builtin_amdgcn_rcpf(1.f + __expf(-x));
}
__device__ __forceinline__ float tanh_f(float x){
  // overflow-safe: exp(2x)=inf -> 1, exp(2x)=0 -> -1
  return 1.f - 2.f*__builtin_amdgcn_rcpf(__expf(2.f*x) + 1.f);
}

// ---------------------------------------------------------------------------
// k_prep: A = softmax(relu(E E^T)), alpha = masked softmax(Tparam),
//         biasG[t][n][o] = E@bp, padded bf16 GRU weights + bias vectors.
// ---------------------------------------------------------------------------
__global__ __launch_bounds__(256) void k_prep(
    const float* __restrict__ E, const float* __restrict__ bp,
    const float* __restrict__ Tp,
    const float* __restrict__ Wih, const float* __restrict__ Whh,
    const float* __restrict__ bih, const float* __restrict__ bhh,
    float* __restrict__ A, float* __restrict__ alpha, float* __restrict__ biasG,
    u16* __restrict__ WihP, u16* __restrict__ WhhP,
    float* __restrict__ brz, float* __restrict__ binv, float* __restrict__ bhnv)
{
  __shared__ float As[3844];
  const int tid = threadIdx.x;
  for (int i = tid; i < 3844; i += 256){
    int nn = i / 62, m = i % 62;
    float s = E[nn*3]*E[m*3] + E[nn*3+1]*E[m*3+1] + E[nn*3+2]*E[m*3+2];
    As[i] = s > 0.f ? s : 0.f;
  }
  __syncthreads();
  if (tid < 62){
    float mx = -1e30f;
    for (int m = 0; m < 62; ++m) mx = fmaxf(mx, As[tid*62+m]);
    float sum = 0.f;
    for (int m = 0; m < 62; ++m) sum += __expf(As[tid*62+m] - mx);
    float inv = 1.f / sum;
    for (int m = 0; m < 62; ++m) A[tid*62+m] = __expf(As[tid*62+m] - mx) * inv;
  }
  if (tid < 8){
    int t = tid;
    float mx = -1e30f;
    for (int s = 0; s <= t; ++s) mx = fmaxf(mx, Tp[t*9+s]);
    float sum = 0.f;
    for (int s = 0; s <= t; ++s) sum += __expf(Tp[t*9+s] - mx);
    float inv = 1.f / sum;
    for (int s = 0; s < 9; ++s)
      alpha[t*9+s] = (s <= t) ? __expf(Tp[t*9+s] - mx) * inv : 0.f;
  }
  for (int i = tid; i < 30752; i += 256){
    int t = i / 3844, rr = i % 3844, nn = rr / 62, o = rr % 62;
    biasG[i] = E[nn*3]*bp[(t*3+0)*62+o] + E[nn*3+1]*bp[(t*3+1)*62+o]
             + E[nn*3+2]*bp[(t*3+2)*62+o];
  }
  // padded weights: gate g rows [g*64, g*64+64), K padded 62->64
  for (int i = tid; i < 12288; i += 256){
    int row = i >> 6, k = i & 63, g = row >> 6, jj = row & 63;
    float vi = 0.f, vh = 0.f;
    if (jj < 62 && k < 62){
      vi = Wih[(g*62+jj)*62 + k];
      vh = Whh[(g*62+jj)*62 + k];
    }
    WihP[i] = f2bf(vi); WhhP[i] = f2bf(vh);
  }
  if (tid < 128){
    int g = tid >> 6, jj = tid & 63;
    brz[tid] = (jj < 62) ? bih[g*62+jj] + bhh[g*62+jj] : 0.f;
  }
  if (tid < 64){
    binv[tid] = (tid < 62) ? bih[124+tid] : 0.f;
    bhnv[tid] = (tid < 62) ? bhh[124+tid] : 0.f;
  }
}

// ---------------------------------------------------------------------------
// k_w: w[t][n][k][c][o] = sum_e E[n,e] * Wp[t,e,k,c,o]   (615040 elems, fp32)
// ---------------------------------------------------------------------------
__global__ __launch_bounds__(256) void k_w(
    const float* __restrict__ E, const float* __restrict__ Wp,
    float* __restrict__ w)
{
  int idx = blockIdx.x*256 + threadIdx.x;
  if (idx >= 615040) return;
  int o = idx % 62; int r = idx / 62;
  int c = r % 10; r /= 10;
  int k = r % 2;  r /= 2;
  int n = r % 62; int t = r / 62;
  float s = 0.f;
  #pragma unroll
  for (int e = 0; e < 3; ++e)
    s += E[n*3+e] * Wp[((((t*3+e)*2+k)*10+c)*62) + o];
  w[idx] = s;
}

// ---------------------------------------------------------------------------
// k_zz: zz[t][b] = sigmoid(sum_p PI[b,p] * Wz[t,p])
// ---------------------------------------------------------------------------
__global__ __launch_bounds__(256) void k_zz(
    const float* __restrict__ PI, const float* __restrict__ Wz,
    float* __restrict__ zz)
{
  const int b = blockIdx.x, tid = threadIdx.x;
  float acc[8] = {0,0,0,0,0,0,0,0};
  const float* pb = PI + (size_t)b*10000;
  for (int p = tid; p < 10000; p += 256){
    float xp = pb[p];
    #pragma unroll
    for (int t = 0; t < 8; ++t) acc[t] += xp * Wz[t*10000 + p];
  }
  __shared__ float red[32];
  int lane = tid & 63, wid = tid >> 6;
  #pragma unroll
  for (int t = 0; t < 8; ++t){
    float v = acc[t];
    v += __shfl_xor(v, 1);  v += __shfl_xor(v, 2);  v += __shfl_xor(v, 4);
    v += __shfl_xor(v, 8);  v += __shfl_xor(v, 16); v += __shfl_xor(v, 32);
    if (lane == 0) red[t*4 + wid] = v;
  }
  __syncthreads();
  if (tid < 8){
    float s = red[tid*4] + red[tid*4+1] + red[tid*4+2] + red[tid*4+3];
    zz[tid*2048 + b] = sigmf(s);
  }
}

// ---------------------------------------------------------------------------
// k_u: U0[t][b][n][c] = zz*x[b,t+1,n,c] + sum_s alpha[t,s] x[b,s,n,c]
//      U1[t][b][n][c] = zz * sum_m A[n,m] x[b,t+1,m,c]        (bf16)
// ---------------------------------------------------------------------------
__global__ __launch_bounds__(256) void k_u(
    const float* __restrict__ x, const float* __restrict__ A,
    const float* __restrict__ alpha, const float* __restrict__ zz,
    u16* __restrict__ U0, u16* __restrict__ U1)
{
  const int b = blockIdx.x, tid = threadIdx.x;
  __shared__ float xs[5580];      // [s][n][c]
  __shared__ float As[3844];
  __shared__ float al[72];
  __shared__ float zzb[8];
  __shared__ u16 u0s[4960], u1s[4960];  // [t][n][c]
  const float* px = x + (size_t)b*5580;
  for (int i = tid; i < 5580; i += 256) xs[i] = px[i];
  for (int i = tid; i < 3844; i += 256) As[i] = A[i];
  if (tid < 72) al[tid] = alpha[tid];
  if (tid < 8) zzb[tid] = zz[tid*2048 + b];
  __syncthreads();
  if (tid < 160){
    int half = tid / 80, tc = tid % 80, t = tc / 10, c = tc % 10, n0 = half*31;
    float acc[31];
    #pragma unroll
    for (int i = 0; i < 31; ++i) acc[i] = 0.f;
    for (int m = 0; m < 62; ++m){
      float xv = xs[(t+1)*620 + m*10 + c];
      #pragma unroll
      for (int i = 0; i < 31; ++i) acc[i] += As[(n0+i)*62 + m] * xv;  // LDS broadcast
    }
    float z = zzb[t];
    for (int i = 0; i < 31; ++i){
      int nn = n0 + i;
      float xw = 0.f;
      #pragma unroll
      for (int s = 0; s < 9; ++s) xw += al[t*9+s] * xs[s*620 + nn*10 + c];
      float u0v = z*xs[(t+1)*620 + nn*10 + c] + xw;
      u0s[t*620 + nn*10 + c] = f2bf(u0v);
      u1s[t*620 + nn*10 + c] = f2bf(z*acc[i]);
    }
  }
  __syncthreads();
  size_t base = (size_t)b*620;
  for (int i = tid; i < 4960; i += 256){
    int t = i / 620, r2 = i % 620;
    size_t g = (size_t)t*2048*620 + base + r2;
    U0[g] = u0s[i]; U1[g] = u1s[i];
  }
}

// ---------------------------------------------------------------------------
// k_gru: fused conv-epilogue + 8-step GRU with MFMA, block = (n, 64 batches).
// Row r = n*2048 + b.  Outputs outSum[n][b] = sum_o hT[r][o].
// ---------------------------------------------------------------------------
__global__ __launch_bounds__(256) void k_gru(
    const u16* __restrict__ U0, const u16* __restrict__ U1,
    const float* __restrict__ wG, const float* __restrict__ zz,
    const float* __restrict__ biasG,
    const u16* __restrict__ WihP, const u16* __restrict__ WhhP,
    const float* __restrict__ brz, const float* __restrict__ binv,
    const float* __restrict__ bhnv, float* __restrict__ outSum)
{
  __shared__ float wstS[1240];        // w[t][n] slice: [k][c][o]
  __shared__ u16 Xs[64*80];           // X_t bf16, row stride 80 (160B, 16B-aligned)
  __shared__ u16 Hhi[64*80];
  __shared__ u16 Hlo[64*80];
  __shared__ float zzs[512];
  __shared__ float biasS[512];
  __shared__ float red[256];

  const int tid = threadIdx.x;
  const int n_idx = blockIdx.x >> 5;
  const int b0 = (blockIdx.x & 31) << 6;
  const int lane = tid & 63;
  const int w_id = tid >> 6;
  const int ln = lane & 15;
  const int hi = lane >> 4;
  const int j = w_id*16 + ln;         // this lane's hidden column

  // persistent B-fragments: wave w owns N-tiles {w, 4+w, 8+w} (gates r,z,n)
  s8v wihF[3][2], whhF[3][2];
  #pragma unroll
  for (int g = 0; g < 3; ++g){
    int nt = g*4 + w_id;
    #pragma unroll
    for (int ks = 0; ks < 2; ++ks){
      int off = (nt*16 + ln)*64 + ks*32 + hi*8;
      wihF[g][ks] = *(const s8v*)(WihP + off);
      whhF[g][ks] = *(const s8v*)(WhhP + off);
    }
  }
  const float bj_r  = brz[j];
  const float bj_z  = brz[64 + j];
  const float bj_in = binv[j];
  const float bj_hn = bhnv[j];

  for (int i = tid; i < 512; i += 256){
    int t = i >> 6, q = i & 63;
    zzs[i] = zz[t*2048 + b0 + q];
    biasS[i] = (q < 62) ? biasG[(t*62 + n_idx)*62 + q] : 0.f;
  }
  for (int i = tid; i < 5120; i += 256){ Hhi[i] = 0; Hlo[i] = 0; }

  float h_reg[16];
  #pragma unroll
  for (int i = 0; i < 16; ++i) h_reg[i] = 0.f;

  const int rowX = tid >> 2;          // h-compute role: batch row
  const int c0 = (tid & 3) << 4;      // h-compute role: o-range start

  for (int t = 0; t < 8; ++t){
    for (int i = tid; i < 1240; i += 256)
      wstS[i] = wG[(size_t)(t*62 + n_idx)*1240 + i];
    __syncthreads();   // bar A: wst ready; prev-step H writes visible

    // ---- conv epilogue: h_t -> Xs (bf16) ----
    {
      int b = b0 + rowX;
      float zzb = zzs[t*64 + rowX];
      const u16* pu0 = U0 + ((size_t)(t*2048 + b)*62 + n_idx)*10;
      const u16* pu1 = U1 + ((size_t)(t*2048 + b)*62 + n_idx)*10;
      float u0f[10], u1f[10];
      #pragma unroll
      for (int c = 0; c < 10; ++c){ u0f[c] = bf2f(pu0[c]); u1f[c] = bf2f(pu1[c]); }
      s8v pk0, pk1;
      #pragma unroll
      for (int oi = 0; oi < 16; ++oi){
        int o = c0 + oi;
        float v = 0.f;
        if (o < 62){
          v = zzb * biasS[t*64 + o];
          #pragma unroll
          for (int c = 0; c < 10; ++c)
            v += u0f[c]*wstS[c*62 + o] + u1f[c]*wstS[620 + c*62 + o];
        }
        u16 bv = f2bf(v);
        if (oi < 8) pk0[oi] = (short)bv; else pk1[oi-8] = (short)bv;
      }
      *(s8v*)&Xs[rowX*80 + c0] = pk0;
      *(s8v*)&Xs[rowX*80 + c0 + 8] = pk1;
    }
    __syncthreads();   // bar B: X ready

    // ---- MFMA: Gx = X@WihP^T, Gh = (Hhi+Hlo)@WhhP^T; r,z share acc ----
    f4v acc_r[4], acc_z[4], acc_xn[4], acc_hn[4];
    #pragma unroll
    for (int mi = 0; mi < 4; ++mi){
      acc_r[mi] = (f4v){0.f,0.f,0.f,0.f};
      acc_z[mi] = (f4v){0.f,0.f,0.f,0.f};
      acc_xn[mi] = (f4v){0.f,0.f,0.f,0.f};
      acc_hn[mi] = (f4v){0.f,0.f,0.f,0.f};
    }
    #pragma unroll
    for (int ks = 0; ks < 2; ++ks){
      #pragma unroll
      for (int mi = 0; mi < 4; ++mi){
        int off = (mi*16 + ln)*80 + ks*32 + hi*8;
        s8v xf = *(const s8v*)&Xs[off];
        s8v hh = *(const s8v*)&Hhi[off];
        s8v hl = *(const s8v*)&Hlo[off];
        acc_r[mi]  = __builtin_amdgcn_mfma_f32_16x16x32_bf16(xf, wihF[0][ks], acc_r[mi], 0,0,0);
        acc_z[mi]  = __builtin_amdgcn_mfma_f32_16x16x32_bf16(xf, wihF[1][ks], acc_z[mi], 0,0,0);
        acc_xn[mi] = __builtin_amdgcn_mfma_f32_16x16x32_bf16(xf, wihF[2][ks], acc_xn[mi], 0,0,0);
        acc_r[mi]  = __builtin_amdgcn_mfma_f32_16x16x32_bf16(hh, whhF[0][ks], acc_r[mi], 0,0,0);
        acc_z[mi]  = __builtin_amdgcn_mfma_f32_16x16x32_bf16(hh, whhF[1][ks], acc_z[mi], 0,0,0);
        acc_hn[mi] = __builtin_amdgcn_mfma_f32_16x16x32_bf16(hh, whhF[2][ks], acc_hn[mi], 0,0,0);
        acc_r[mi]  = __builtin_amdgcn_mfma_f32_16x16x32_bf16(hl, whhF[0][ks], acc_r[mi], 0,0,0);
        acc_z[mi]  = __builtin_amdgcn_mfma_f32_16x16x32_bf16(hl, whhF[1][ks], acc_z[mi], 0,0,0);
        acc_hn[mi] = __builtin_amdgcn_mfma_f32_16x16x32_bf16(hl, whhF[2][ks], acc_hn[mi], 0,0,0);
      }
    }
    __syncthreads();   // bar C: all LDS frag reads complete before H rewrite

    // ---- gates (fp32), write hi/lo bf16 H for next step ----
    const bool last = (t == 7);
    #pragma unroll
    for (int mi = 0; mi < 4; ++mi){
      #pragma unroll
      for (int rg = 0; rg < 4; ++rg){
        float r  = sigmf(acc_r[mi][rg] + bj_r);
        float zg = sigmf(acc_z[mi][rg] + bj_z);
        float ng = tanh_f(acc_xn[mi][rg] + bj_in + r*(acc_hn[mi][rg] + bj_hn));
        int idx = mi*4 + rg;
        float h = h_reg[idx];
        float hn2 = ng + zg*(h - ng);
        h_reg[idx] = hn2;
        if (!last){
          int rowl = mi*16 + hi*4 + rg;
          u16 hb = f2bf(hn2);
          float hf = bf2f(hb);
          u16 lb = f2bf(hn2 - hf);
          Hhi[rowl*80 + j] = hb;
          Hlo[rowl*80 + j] = lb;
        }
      }
    }
  }

  // ---- row-sum over hidden dim ----
  #pragma unroll
  for (int mi = 0; mi < 4; ++mi){
    #pragma unroll
    for (int rg = 0; rg < 4; ++rg){
      float v = h_reg[mi*4 + rg];
      v += __shfl_xor(v, 1); v += __shfl_xor(v, 2);
      v += __shfl_xor(v, 4); v += __shfl_xor(v, 8);
      if (ln == 0) red[w_id*64 + mi*16 + hi*4 + rg] = v;
    }
  }
  __syncthreads();
  if (tid < 64)
    outSum[(size_t)n_idx*2048 + b0 + tid] =
        red[tid] + red[64+tid] + red[128+tid] + red[192+tid];
}

// ---------------------------------------------------------------------------
// k_mlp: out = relu(relu(vec@W1^T + b1)@W2^T + b2), vec[n] = outSum[n][b]
// ---------------------------------------------------------------------------
__global__ __launch_bounds__(64) void k_mlp(
    const float* __restrict__ outSum,
    const float* __restrict__ W1, const float* __restrict__ b1,
    const float* __restrict__ W2, const float* __restrict__ b2,
    float* __restrict__ out)
{
  const int b = blockIdx.x, tid = threadIdx.x;
  __shared__ float vec[62];
  __shared__ float o1[256];
  if (tid < 62) vec[tid] = outSum[(size_t)tid*2048 + b];
  __syncthreads();
  for (int jj = tid; jj < 256; jj += 64){
    float s = b1[jj];
    for (int nn = 0; nn < 62; ++nn) s += vec[nn]*W1[jj*62 + nn];
    o1[jj] = fmaxf(s, 0.f);
  }
  __syncthreads();
  if (tid < 3){
    float s = b2[tid];
    for (int k = 0; k < 256; ++k) s += o1[k]*W2[tid*256 + k];
    out[b*3 + tid] = fmaxf(s, 0.f);
  }
}

// ---------------------------------------------------------------------------
extern "C" void kernel_launch(void* const* d_in, const int* in_sizes, int n_in,
                              void* d_out, int out_size, void* d_ws, size_t ws_size,
                              hipStream_t stream)
{
  const float* x   = (const float*)d_in[0];
  const float* PI  = (const float*)d_in[1];
  const float* E   = (const float*)d_in[2];
  const float* Wp  = (const float*)d_in[3];
  const float* bp  = (const float*)d_in[4];
  const float* Tp  = (const float*)d_in[5];
  const float* Wz  = (const float*)d_in[6];
  const float* Wih = (const float*)d_in[7];
  const float* Whh = (const float*)d_in[8];
  const float* bih = (const float*)d_in[9];
  const float* bhh = (const float*)d_in[10];
  const float* W1  = (const float*)d_in[11];
  const float* b1  = (const float*)d_in[12];
  const float* W2  = (const float*)d_in[13];
  const float* b2  = (const float*)d_in[14];
  float* out = (float*)d_out;

  char* ws = (char*)d_ws;
  size_t off = 0;
  auto take = [&](size_t bytes)->char*{
    char* p = ws + off; off = (off + bytes + 255) & ~(size_t)255; return p;
  };
  float* pA     = (float*)take(3844*4);
  float* palpha = (float*)take(72*4);
  float* pbias  = (float*)take(30752*4);
  float* pzz    = (float*)take(16384*4);
  u16*   pWihP  = (u16*)take(12288*2);
  u16*   pWhhP  = (u16*)take(12288*2);
  float* pbrz   = (float*)take(128*4);
  float* pbin   = (float*)take(64*4);
  float* pbhn   = (float*)take(64*4);
  float* pw     = (float*)take((size_t)615040*4);
  u16*   pU0    = (u16*)take((size_t)10158080*2);
  u16*   pU1    = (u16*)take((size_t)10158080*2);
  float* pos    = (float*)take((size_t)126976*4);

  k_prep<<<1, 256, 0, stream>>>(E, bp, Tp, Wih, Whh, bih, bhh,
                                pA, palpha, pbias, pWihP, pWhhP, pbrz, pbin, pbhn);
  k_w<<<2403, 256, 0, stream>>>(E, Wp, pw);
  k_zz<<<2048, 256, 0, stream>>>(PI, Wz, pzz);
  k_u<<<2048, 256, 0, stream>>>(x, pA, palpha, pzz, pU0, pU1);
  k_gru<<<1984, 256, 0, stream>>>(pU0, pU1, pw, pzz, pbias, pWihP, pWhhP,
                                  pbrz, pbin, pbhn, pos);
  k_mlp<<<2048, 64, 0, stream>>>(pos, W1, b1, W2, b2, out);
}

// Round 2
// 339.250 us; speedup vs baseline: 1.8803x; 1.8803x over previous
//
#include <hip/hip_runtime.h>

typedef unsigned short u16;
typedef __attribute__((ext_vector_type(8))) short s8v;   // 8 x bf16 (as shorts)
typedef __attribute__((ext_vector_type(4))) float f4v;

__device__ __forceinline__ u16 f2bf(float f){
  unsigned u = __float_as_uint(f);
  return (u16)((u + 0x7FFFu + ((u >> 16) & 1u)) >> 16);
}
__device__ __forceinline__ float bf2f(u16 h){
  return __uint_as_float(((unsigned)h) << 16);
}
__device__ __forceinline__ float sigmf(float x){
  return __builtin_amdgcn_rcpf(1.f + __expf(-x));
}
__device__ __forceinline__ float tanh_f(float x){
  return 1.f - 2.f*__builtin_amdgcn_rcpf(__expf(2.f*x) + 1.f);
}
__device__ __forceinline__ void gload16(const void* g, void* l){
  __builtin_amdgcn_global_load_lds(
      (const __attribute__((address_space(1))) unsigned int*)g,
      (__attribute__((address_space(3))) unsigned int*)l, 16, 0, 0);
}

// ---------------------------------------------------------------------------
// k_prep: A = softmax(relu(E E^T)), alpha = masked softmax(Tparam),
//         biasG[t][n][o] = E@bp, padded bf16 GRU weights + bias vectors.
// ---------------------------------------------------------------------------
__global__ __launch_bounds__(256) void k_prep(
    const float* __restrict__ E, const float* __restrict__ bp,
    const float* __restrict__ Tp,
    const float* __restrict__ Wih, const float* __restrict__ Whh,
    const float* __restrict__ bih, const float* __restrict__ bhh,
    float* __restrict__ A, float* __restrict__ alpha, float* __restrict__ biasG,
    u16* __restrict__ WihP, u16* __restrict__ WhhP,
    float* __restrict__ brz, float* __restrict__ binv, float* __restrict__ bhnv)
{
  __shared__ float As[3844];
  const int tid = threadIdx.x;
  for (int i = tid; i < 3844; i += 256){
    int nn = i / 62, m = i % 62;
    float s = E[nn*3]*E[m*3] + E[nn*3+1]*E[m*3+1] + E[nn*3+2]*E[m*3+2];
    As[i] = s > 0.f ? s : 0.f;
  }
  __syncthreads();
  if (tid < 62){
    float mx = -1e30f;
    for (int m = 0; m < 62; ++m) mx = fmaxf(mx, As[tid*62+m]);
    float sum = 0.f;
    for (int m = 0; m < 62; ++m) sum += __expf(As[tid*62+m] - mx);
    float inv = 1.f / sum;
    for (int m = 0; m < 62; ++m) A[tid*62+m] = __expf(As[tid*62+m] - mx) * inv;
  }
  if (tid < 8){
    int t = tid;
    float mx = -1e30f;
    for (int s = 0; s <= t; ++s) mx = fmaxf(mx, Tp[t*9+s]);
    float sum = 0.f;
    for (int s = 0; s <= t; ++s) sum += __expf(Tp[t*9+s] - mx);
    float inv = 1.f / sum;
    for (int s = 0; s < 9; ++s)
      alpha[t*9+s] = (s <= t) ? __expf(Tp[t*9+s] - mx) * inv : 0.f;
  }
  for (int i = tid; i < 30752; i += 256){
    int t = i / 3844, rr = i % 3844, nn = rr / 62, o = rr % 62;
    biasG[i] = E[nn*3]*bp[(t*3+0)*62+o] + E[nn*3+1]*bp[(t*3+1)*62+o]
             + E[nn*3+2]*bp[(t*3+2)*62+o];
  }
  // padded weights: gate g rows [g*64, g*64+64), K padded 62->64
  for (int i = tid; i < 12288; i += 256){
    int row = i >> 6, k = i & 63, g = row >> 6, jj = row & 63;
    float vi = 0.f, vh = 0.f;
    if (jj < 62 && k < 62){
      vi = Wih[(g*62+jj)*62 + k];
      vh = Whh[(g*62+jj)*62 + k];
    }
    WihP[i] = f2bf(vi); WhhP[i] = f2bf(vh);
  }
  if (tid < 128){
    int g = tid >> 6, jj = tid & 63;
    brz[tid] = (jj < 62) ? bih[g*62+jj] + bhh[g*62+jj] : 0.f;
  }
  if (tid < 64){
    binv[tid] = (tid < 62) ? bih[124+tid] : 0.f;
    bhnv[tid] = (tid < 62) ? bhh[124+tid] : 0.f;
  }
}

// ---------------------------------------------------------------------------
// k_w2: w2[((t*62+n)*64+o)*32 + k] bf16, k = 2*c + link (k>=20 or o>=62 -> 0)
// ---------------------------------------------------------------------------
__global__ __launch_bounds__(256) void k_w2(
    const float* __restrict__ E, const float* __restrict__ Wp,
    u16* __restrict__ w2)
{
  int idx = blockIdx.x*256 + threadIdx.x;
  if (idx >= 8*62*64*32) return;
  int k = idx & 31; int r = idx >> 5;
  int o = r & 63; r >>= 6;
  int n = r % 62; int t = r / 62;
  float v = 0.f;
  if (o < 62 && k < 20){
    int c = k >> 1, kl = k & 1;
    #pragma unroll
    for (int e = 0; e < 3; ++e)
      v += E[n*3+e] * Wp[((((t*3+e)*2+kl)*10+c)*62) + o];
  }
  w2[idx] = f2bf(v);
}

// ---------------------------------------------------------------------------
// k_zz: zz[t][b] = sigmoid(sum_p PI[b,p] * Wz[t,p])
// ---------------------------------------------------------------------------
__global__ __launch_bounds__(256) void k_zz(
    const float* __restrict__ PI, const float* __restrict__ Wz,
    float* __restrict__ zz)
{
  const int b = blockIdx.x, tid = threadIdx.x;
  float acc[8] = {0,0,0,0,0,0,0,0};
  const float* pb = PI + (size_t)b*10000;
  for (int p = tid; p < 10000; p += 256){
    float xp = pb[p];
    #pragma unroll
    for (int t = 0; t < 8; ++t) acc[t] += xp * Wz[t*10000 + p];
  }
  __shared__ float red[32];
  int lane = tid & 63, wid = tid >> 6;
  #pragma unroll
  for (int t = 0; t < 8; ++t){
    float v = acc[t];
    v += __shfl_xor(v, 1);  v += __shfl_xor(v, 2);  v += __shfl_xor(v, 4);
    v += __shfl_xor(v, 8);  v += __shfl_xor(v, 16); v += __shfl_xor(v, 32);
    if (lane == 0) red[t*4 + wid] = v;
  }
  __syncthreads();
  if (tid < 8){
    float s = red[tid*4] + red[tid*4+1] + red[tid*4+2] + red[tid*4+3];
    zz[tid*2048 + b] = sigmf(s);
  }
}

// ---------------------------------------------------------------------------
// k_u: per batch b, compute U0/U1 and write packed interleaved bf16
//      U01[((t*62+n)*2048+b)*32 + k],  k=2c+part (part0=U0, part1=U1), pad 32
// ---------------------------------------------------------------------------
__global__ __launch_bounds__(256) void k_u(
    const float* __restrict__ x, const float* __restrict__ A,
    const float* __restrict__ alpha, const float* __restrict__ zz,
    u16* __restrict__ U01)
{
  const int b = blockIdx.x, tid = threadIdx.x;
  __shared__ float xs[5580];      // [s][n][c]
  __shared__ float As[3844];
  __shared__ float al[72];
  __shared__ float zzb[8];
  __shared__ u16 u0s[4960], u1s[4960];  // [t][n][c]
  const float* px = x + (size_t)b*5580;
  for (int i = tid; i < 5580; i += 256) xs[i] = px[i];
  for (int i = tid; i < 3844; i += 256) As[i] = A[i];
  if (tid < 72) al[tid] = alpha[tid];
  if (tid < 8) zzb[tid] = zz[tid*2048 + b];
  __syncthreads();
  if (tid < 160){
    int half = tid / 80, tc = tid % 80, t = tc / 10, c = tc % 10, n0 = half*31;
    float acc[31];
    #pragma unroll
    for (int i = 0; i < 31; ++i) acc[i] = 0.f;
    for (int m = 0; m < 62; ++m){
      float xv = xs[(t+1)*620 + m*10 + c];
      #pragma unroll
      for (int i = 0; i < 31; ++i) acc[i] += As[(n0+i)*62 + m] * xv;  // LDS broadcast
    }
    float z = zzb[t];
    for (int i = 0; i < 31; ++i){
      int nn = n0 + i;
      float xw = 0.f;
      #pragma unroll
      for (int s = 0; s < 9; ++s) xw += al[t*9+s] * xs[s*620 + nn*10 + c];
      float u0v = z*xs[(t+1)*620 + nn*10 + c] + xw;
      u0s[t*620 + nn*10 + c] = f2bf(u0v);
      u1s[t*620 + nn*10 + c] = f2bf(z*acc[i]);
    }
  }
  __syncthreads();
  // packed writeout: 8*62 rows of 32 u16 (64B), as 4 x 16B chunks per row
  for (int i = tid; i < 1984; i += 256){
    int t = i / 248, r = i % 248, n = r >> 2, q = r & 3;
    s8v pk;
    #pragma unroll
    for (int jj = 0; jj < 8; ++jj){
      int k = q*8 + jj;
      u16 v = 0;
      if (k < 20){
        int c = k >> 1;
        v = (k & 1) ? u1s[t*620 + n*10 + c] : u0s[t*620 + n*10 + c];
      }
      pk[jj] = (short)v;
    }
    *(s8v*)(U01 + ((size_t)(t*62+n)*2048 + b)*32 + q*8) = pk;
  }
}

// ---------------------------------------------------------------------------
// k_gru: 3-GEMM fused step: X = U01@w2 + zz*bias (MFMA), gates = X@Wih^T +
//        (Hhi+Hlo)@Whh^T (MFMA), gate nonlinearity (VALU).
// Block = (n, 32-batch tile), 4 waves; wave w owns hidden/o tile w*16..w*16+15.
// ---------------------------------------------------------------------------
__global__ __launch_bounds__(256) void k_gru(
    const u16* __restrict__ U01, const u16* __restrict__ w2,
    const float* __restrict__ zz, const float* __restrict__ biasG,
    const u16* __restrict__ WihP, const u16* __restrict__ WhhP,
    const float* __restrict__ brz, const float* __restrict__ binv,
    const float* __restrict__ bhnv, float* __restrict__ outSum)
{
  __shared__ u16 Us[2][32*32];    // [buf][b][k]  (k=32, 64B rows)
  __shared__ u16 Xs[32*72];       // [b][o] stride 72 (144B, 16B-aligned)
  __shared__ u16 Hh[32*72];
  __shared__ u16 Hl[32*72];
  __shared__ float zzs[8*32];
  __shared__ float red[4*32];

  const int tid = threadIdx.x;
  const int n_idx = blockIdx.x >> 6;
  const int b0 = (blockIdx.x & 63) << 5;
  const int lane = tid & 63;
  const int w_id = tid >> 6;
  const int ln = lane & 15;
  const int hi = lane >> 4;
  const int j = w_id*16 + ln;     // this lane's hidden col (and conv o col)

  // persistent gate weight B-fragments (48 VGPR)
  s8v wihF[3][2], whhF[3][2];
  #pragma unroll
  for (int g = 0; g < 3; ++g){
    #pragma unroll
    for (int ks = 0; ks < 2; ++ks){
      int off = (g*64 + j)*64 + ks*32 + hi*8;
      wihF[g][ks] = *(const s8v*)(WihP + off);
      whhF[g][ks] = *(const s8v*)(WhhP + off);
    }
  }
  const float bj_r  = brz[j];
  const float bj_z  = brz[64 + j];
  const float bj_in = binv[j];
  const float bj_hn = bhnv[j];
  float biasA[8];
  #pragma unroll
  for (int t = 0; t < 8; ++t)
    biasA[t] = (j < 62) ? biasG[(t*62 + n_idx)*62 + j] : 0.f;

  {
    int t = tid >> 5, rw = tid & 31;
    zzs[tid] = zz[t*2048 + b0 + rw];
  }
  for (int i = tid; i < 2304; i += 256){ Hh[i] = 0; Hl[i] = 0; }

  // stage Us[0] (t=0): 32 rows x 64B = 2KB
  if (tid < 128){
    const u16* g = U01 + ((size_t)(0*62 + n_idx)*2048 + b0)*32;
    gload16(g + tid*8, &Us[0][tid*8]);
  }
  __syncthreads();

  float h_reg[8];
  #pragma unroll
  for (int i = 0; i < 8; ++i) h_reg[i] = 0.f;

  int cur = 0;
  for (int t = 0; t < 8; ++t){
    // prefetch next step's U tile (drains at bar1, consumed next iter)
    if (t < 7 && tid < 128){
      const u16* g = U01 + ((size_t)((t+1)*62 + n_idx)*2048 + b0)*32;
      gload16(g + tid*8, &Us[cur^1][tid*8]);
    }
    // ---- conv GEMM: X[b][o] = U01 @ w2 + zz*bias ----
    s8v wf = *(const s8v*)(w2 + ((size_t)(t*62 + n_idx)*64 + j)*32 + hi*8);
    f4v accc[2];
    #pragma unroll
    for (int mi = 0; mi < 2; ++mi){
      #pragma unroll
      for (int rg = 0; rg < 4; ++rg)
        accc[mi][rg] = zzs[t*32 + mi*16 + hi*4 + rg] * biasA[t];
      s8v af = *(const s8v*)&Us[cur][(mi*16 + ln)*32 + hi*8];
      accc[mi] = __builtin_amdgcn_mfma_f32_16x16x32_bf16(af, wf, accc[mi], 0,0,0);
    }
    #pragma unroll
    for (int mi = 0; mi < 2; ++mi)
      #pragma unroll
      for (int rg = 0; rg < 4; ++rg)
        Xs[(mi*16 + hi*4 + rg)*72 + j] = f2bf(accc[mi][rg]);
    __syncthreads();   // bar1: X ready, prefetch drained

    // ---- gate GEMM ----
    f4v ar[2], az[2], axn[2], ahn[2];
    #pragma unroll
    for (int mi = 0; mi < 2; ++mi){
      ar[mi] = (f4v){0.f,0.f,0.f,0.f};  az[mi] = (f4v){0.f,0.f,0.f,0.f};
      axn[mi] = (f4v){0.f,0.f,0.f,0.f}; ahn[mi] = (f4v){0.f,0.f,0.f,0.f};
    }
    #pragma unroll
    for (int ks = 0; ks < 2; ++ks){
      #pragma unroll
      for (int mi = 0; mi < 2; ++mi){
        int off = (mi*16 + ln)*72 + ks*32 + hi*8;
        s8v xf = *(const s8v*)&Xs[off];
        s8v hh = *(const s8v*)&Hh[off];
        s8v hl = *(const s8v*)&Hl[off];
        ar[mi]  = __builtin_amdgcn_mfma_f32_16x16x32_bf16(xf, wihF[0][ks], ar[mi], 0,0,0);
        az[mi]  = __builtin_amdgcn_mfma_f32_16x16x32_bf16(xf, wihF[1][ks], az[mi], 0,0,0);
        axn[mi] = __builtin_amdgcn_mfma_f32_16x16x32_bf16(xf, wihF[2][ks], axn[mi], 0,0,0);
        ar[mi]  = __builtin_amdgcn_mfma_f32_16x16x32_bf16(hh, whhF[0][ks], ar[mi], 0,0,0);
        az[mi]  = __builtin_amdgcn_mfma_f32_16x16x32_bf16(hh, whhF[1][ks], az[mi], 0,0,0);
        ahn[mi] = __builtin_amdgcn_mfma_f32_16x16x32_bf16(hh, whhF[2][ks], ahn[mi], 0,0,0);
        ar[mi]  = __builtin_amdgcn_mfma_f32_16x16x32_bf16(hl, whhF[0][ks], ar[mi], 0,0,0);
        az[mi]  = __builtin_amdgcn_mfma_f32_16x16x32_bf16(hl, whhF[1][ks], az[mi], 0,0,0);
        ahn[mi] = __builtin_amdgcn_mfma_f32_16x16x32_bf16(hl, whhF[2][ks], ahn[mi], 0,0,0);
      }
    }
    __syncthreads();   // bar2: all H/X frag reads complete

    // ---- gates + H update ----
    const bool last = (t == 7);
    #pragma unroll
    for (int mi = 0; mi < 2; ++mi){
      #pragma unroll
      for (int rg = 0; rg < 4; ++rg){
        float r  = sigmf(ar[mi][rg] + bj_r);
        float zg = sigmf(az[mi][rg] + bj_z);
        float ng = tanh_f(axn[mi][rg] + bj_in + r*(ahn[mi][rg] + bj_hn));
        int idx = mi*4 + rg;
        float h = h_reg[idx];
        float hn2 = ng + zg*(h - ng);
        h_reg[idx] = hn2;
        if (!last){
          int row = mi*16 + hi*4 + rg;
          u16 hb = f2bf(hn2);
          Hh[row*72 + j] = hb;
          Hl[row*72 + j] = f2bf(hn2 - bf2f(hb));
        }
      }
    }
    __syncthreads();   // bar3: H written
    cur ^= 1;
  }

  // ---- row-sum over hidden dim ----
  #pragma unroll
  for (int mi = 0; mi < 2; ++mi){
    #pragma unroll
    for (int rg = 0; rg < 4; ++rg){
      float v = h_reg[mi*4 + rg];
      v += __shfl_xor(v, 1); v += __shfl_xor(v, 2);
      v += __shfl_xor(v, 4); v += __shfl_xor(v, 8);
      if (ln == 0) red[w_id*32 + mi*16 + hi*4 + rg] = v;
    }
  }
  __syncthreads();
  if (tid < 32)
    outSum[(size_t)n_idx*2048 + b0 + tid] =
        red[tid] + red[32+tid] + red[64+tid] + red[96+tid];
}

// ---------------------------------------------------------------------------
// k_mlp: out = relu(relu(vec@W1^T + b1)@W2^T + b2), vec[n] = outSum[n][b]
// ---------------------------------------------------------------------------
__global__ __launch_bounds__(64) void k_mlp(
    const float* __restrict__ outSum,
    const float* __restrict__ W1, const float* __restrict__ b1,
    const float* __restrict__ W2, const float* __restrict__ b2,
    float* __restrict__ out)
{
  const int b = blockIdx.x, tid = threadIdx.x;
  __shared__ float vec[62];
  __shared__ float o1[256];
  if (tid < 62) vec[tid] = outSum[(size_t)tid*2048 + b];
  __syncthreads();
  for (int jj = tid; jj < 256; jj += 64){
    float s = b1[jj];
    for (int nn = 0; nn < 62; ++nn) s += vec[nn]*W1[jj*62 + nn];
    o1[jj] = fmaxf(s, 0.f);
  }
  __syncthreads();
  if (tid < 3){
    float s = b2[tid];
    for (int k = 0; k < 256; ++k) s += o1[k]*W2[tid*256 + k];
    out[b*3 + tid] = fmaxf(s, 0.f);
  }
}

// ---------------------------------------------------------------------------
extern "C" void kernel_launch(void* const* d_in, const int* in_sizes, int n_in,
                              void* d_out, int out_size, void* d_ws, size_t ws_size,
                              hipStream_t stream)
{
  const float* x   = (const float*)d_in[0];
  const float* PI  = (const float*)d_in[1];
  const float* E   = (const float*)d_in[2];
  const float* Wp  = (const float*)d_in[3];
  const float* bp  = (const float*)d_in[4];
  const float* Tp  = (const float*)d_in[5];
  const float* Wz  = (const float*)d_in[6];
  const float* Wih = (const float*)d_in[7];
  const float* Whh = (const float*)d_in[8];
  const float* bih = (const float*)d_in[9];
  const float* bhh = (const float*)d_in[10];
  const float* W1  = (const float*)d_in[11];
  const float* b1  = (const float*)d_in[12];
  const float* W2  = (const float*)d_in[13];
  const float* b2  = (const float*)d_in[14];
  float* out = (float*)d_out;

  char* ws = (char*)d_ws;
  size_t off = 0;
  auto take = [&](size_t bytes)->char*{
    char* p = ws + off; off = (off + bytes + 255) & ~(size_t)255; return p;
  };
  float* pA     = (float*)take(3844*4);
  float* palpha = (float*)take(72*4);
  float* pbias  = (float*)take(30752*4);
  float* pzz    = (float*)take(16384*4);
  u16*   pWihP  = (u16*)take(12288*2);
  u16*   pWhhP  = (u16*)take(12288*2);
  float* pbrz   = (float*)take(128*4);
  float* pbin   = (float*)take(64*4);
  float* pbhn   = (float*)take(64*4);
  u16*   pw2    = (u16*)take((size_t)1015808*2);
  u16*   pU01   = (u16*)take((size_t)32505856*2);
  float* pos    = (float*)take((size_t)126976*4);

  k_prep<<<1, 256, 0, stream>>>(E, bp, Tp, Wih, Whh, bih, bhh,
                                pA, palpha, pbias, pWihP, pWhhP, pbrz, pbin, pbhn);
  k_w2<<<3968, 256, 0, stream>>>(E, Wp, pw2);
  k_zz<<<2048, 256, 0, stream>>>(PI, Wz, pzz);
  k_u<<<2048, 256, 0, stream>>>(x, pA, palpha, pzz, pU01);
  k_gru<<<3968, 256, 0, stream>>>(pU01, pw2, pzz, pbias, pWihP, pWhhP,
                                  pbrz, pbin, pbhn, pos);
  k_mlp<<<2048, 64, 0, stream>>>(pos, W1, b1, W2, b2, out);
}

// Round 3
// 271.315 us; speedup vs baseline: 2.3511x; 1.2504x over previous
//
#include <hip/hip_runtime.h>
#include <hip/hip_bf16.h>

typedef unsigned short u16;
typedef __attribute__((ext_vector_type(8))) short s8v;   // 8 x bf16 (as shorts)
typedef __attribute__((ext_vector_type(4))) float f4v;

__device__ __forceinline__ u16 f2bf(float f){
  union { __hip_bfloat16 b; u16 u; } v;
  v.b = __float2bfloat16(f);     // RNE; compiler fuses pairs into v_cvt_pk_bf16_f32
  return v.u;
}
__device__ __forceinline__ float bf2f(u16 h){
  return __uint_as_float(((unsigned)h) << 16);
}
__device__ __forceinline__ float sigmf(float x){
  return __builtin_amdgcn_rcpf(1.f + __expf(-x));
}
__device__ __forceinline__ float tanh_f(float x){
  return 1.f - 2.f*__builtin_amdgcn_rcpf(__expf(2.f*x) + 1.f);
}

// ---------------------------------------------------------------------------
// k_prep: A = softmax(relu(E E^T)), alpha = masked softmax(Tparam),
//         padded bf16 GRU weights + bias vectors.
// ---------------------------------------------------------------------------
__global__ __launch_bounds__(256) void k_prep(
    const float* __restrict__ E, const float* __restrict__ Tp,
    const float* __restrict__ Wih, const float* __restrict__ Whh,
    const float* __restrict__ bih, const float* __restrict__ bhh,
    float* __restrict__ A, float* __restrict__ alpha,
    u16* __restrict__ WihP, u16* __restrict__ WhhP,
    float* __restrict__ brz, float* __restrict__ binv, float* __restrict__ bhnv)
{
  __shared__ float As[3844];
  const int tid = threadIdx.x;
  for (int i = tid; i < 3844; i += 256){
    int nn = i / 62, m = i % 62;
    float s = E[nn*3]*E[m*3] + E[nn*3+1]*E[m*3+1] + E[nn*3+2]*E[m*3+2];
    As[i] = s > 0.f ? s : 0.f;
  }
  __syncthreads();
  if (tid < 62){
    float mx = -1e30f;
    for (int m = 0; m < 62; ++m) mx = fmaxf(mx, As[tid*62+m]);
    float sum = 0.f;
    for (int m = 0; m < 62; ++m) sum += __expf(As[tid*62+m] - mx);
    float inv = 1.f / sum;
    for (int m = 0; m < 62; ++m) A[tid*62+m] = __expf(As[tid*62+m] - mx) * inv;
  }
  if (tid < 8){
    int t = tid;
    float mx = -1e30f;
    for (int s = 0; s <= t; ++s) mx = fmaxf(mx, Tp[t*9+s]);
    float sum = 0.f;
    for (int s = 0; s <= t; ++s) sum += __expf(Tp[t*9+s] - mx);
    float inv = 1.f / sum;
    for (int s = 0; s < 9; ++s)
      alpha[t*9+s] = (s <= t) ? __expf(Tp[t*9+s] - mx) * inv : 0.f;
  }
  // padded weights: gate g rows [g*64, g*64+64), K padded 62->64
  for (int i = tid; i < 12288; i += 256){
    int row = i >> 6, k = i & 63, g = row >> 6, jj = row & 63;
    float vi = 0.f, vh = 0.f;
    if (jj < 62 && k < 62){
      vi = Wih[(g*62+jj)*62 + k];
      vh = Whh[(g*62+jj)*62 + k];
    }
    WihP[i] = f2bf(vi); WhhP[i] = f2bf(vh);
  }
  if (tid < 128){
    int g = tid >> 6, jj = tid & 63;
    brz[tid] = (jj < 62) ? bih[g*62+jj] + bhh[g*62+jj] : 0.f;
  }
  if (tid < 64){
    binv[tid] = (tid < 62) ? bih[124+tid] : 0.f;
    bhnv[tid] = (tid < 62) ? bhh[124+tid] : 0.f;
  }
}

// ---------------------------------------------------------------------------
// k_w2: w2[((t*62+n)*64+o)*32 + k] bf16, k = 2*c + link (k>=20 or o>=62 -> 0)
// ---------------------------------------------------------------------------
__global__ __launch_bounds__(256) void k_w2(
    const float* __restrict__ E, const float* __restrict__ Wp,
    u16* __restrict__ w2)
{
  int idx = blockIdx.x*256 + threadIdx.x;
  if (idx >= 8*62*64*32) return;
  int k = idx & 31; int r = idx >> 5;
  int o = r & 63; r >>= 6;
  int n = r % 62; int t = r / 62;
  float v = 0.f;
  if (o < 62 && k < 20){
    int c = k >> 1, kl = k & 1;
    #pragma unroll
    for (int e = 0; e < 3; ++e)
      v += E[n*3+e] * Wp[((((t*3+e)*2+kl)*10+c)*62) + o];
  }
  w2[idx] = f2bf(v);
}

// ---------------------------------------------------------------------------
// k_zz: 4 batches per block; zz[t][b] = sigmoid(sum_p PI[b,p] * Wz[t,p])
// ---------------------------------------------------------------------------
__global__ __launch_bounds__(256) void k_zz(
    const float* __restrict__ PI, const float* __restrict__ Wz,
    float* __restrict__ zzO)
{
  const int b0 = blockIdx.x*4, tid = threadIdx.x;
  float acc[32];
  #pragma unroll
  for (int i = 0; i < 32; ++i) acc[i] = 0.f;
  for (int p = tid; p < 10000; p += 256){
    float x0 = PI[(size_t)(b0+0)*10000 + p];
    float x1 = PI[(size_t)(b0+1)*10000 + p];
    float x2 = PI[(size_t)(b0+2)*10000 + p];
    float x3 = PI[(size_t)(b0+3)*10000 + p];
    #pragma unroll
    for (int t = 0; t < 8; ++t){
      float wv = Wz[t*10000 + p];
      acc[t*4+0] += x0*wv; acc[t*4+1] += x1*wv;
      acc[t*4+2] += x2*wv; acc[t*4+3] += x3*wv;
    }
  }
  __shared__ float red[128];
  int lane = tid & 63, wid = tid >> 6;
  #pragma unroll
  for (int i = 0; i < 32; ++i){
    float v = acc[i];
    v += __shfl_xor(v, 1);  v += __shfl_xor(v, 2);  v += __shfl_xor(v, 4);
    v += __shfl_xor(v, 8);  v += __shfl_xor(v, 16); v += __shfl_xor(v, 32);
    if (lane == 0) red[i*4 + wid] = v;
  }
  __syncthreads();
  if (tid < 32){
    float s = red[tid*4] + red[tid*4+1] + red[tid*4+2] + red[tid*4+3];
    int t = tid >> 2, bq = tid & 3;
    zzO[t*2048 + b0 + bq] = sigmf(s);
  }
}

// ---------------------------------------------------------------------------
// k_u: per batch b; thread = (t, n-quad, c-half); writes packed interleaved
//      U01[((t*62+n)*2048+b)*32 + k], k=2c+part (0=U0,1=U1), pad to 32 with 0
// ---------------------------------------------------------------------------
__global__ __launch_bounds__(256) void k_u(
    const float* __restrict__ x, const float* __restrict__ A,
    const float* __restrict__ alpha, const float* __restrict__ zz,
    u16* __restrict__ U01)
{
  const int b = blockIdx.x, tid = threadIdx.x;
  __shared__ float xs[5580];      // [s][n][c]
  __shared__ float As[3844];
  __shared__ float al[72];
  __shared__ float zzb[8];
  const float4* px = (const float4*)(x + (size_t)b*5580);
  for (int i = tid; i < 1395; i += 256) ((float4*)xs)[i] = px[i];
  for (int i = tid; i < 961; i += 256) ((float4*)As)[i] = ((const float4*)A)[i];
  if (tid < 72) al[tid] = alpha[tid];
  if (tid < 8) zzb[tid] = zz[tid*2048 + b];
  __syncthreads();

  const int t = tid >> 5, nq = (tid >> 1) & 15, ch = tid & 1;
  const int n0 = nq*4, c0 = ch*5;
  float acc[4][5];
  #pragma unroll
  for (int i = 0; i < 4; ++i)
    #pragma unroll
    for (int c = 0; c < 5; ++c) acc[i][c] = 0.f;
  for (int m = 0; m < 62; ++m){
    float xv[5];
    #pragma unroll
    for (int c = 0; c < 5; ++c) xv[c] = xs[(t+1)*620 + m*10 + c0 + c];
    #pragma unroll
    for (int i = 0; i < 4; ++i){
      int n = n0 + i;
      float a = (n < 62) ? As[n*62 + m] : 0.f;
      #pragma unroll
      for (int c = 0; c < 5; ++c) acc[i][c] += a*xv[c];
    }
  }
  float alr[9];
  #pragma unroll
  for (int s = 0; s < 9; ++s) alr[s] = al[t*9+s];
  float z = zzb[t];
  #pragma unroll
  for (int i = 0; i < 4; ++i){
    int n = n0 + i;
    if (n < 62){
      unsigned pk[5];
      #pragma unroll
      for (int c = 0; c < 5; ++c){
        int cc = c0 + c;
        float xw = 0.f;
        #pragma unroll
        for (int s = 0; s < 9; ++s) xw += alr[s]*xs[s*620 + n*10 + cc];
        float u0 = z*xs[(t+1)*620 + n*10 + cc] + xw;
        float u1 = z*acc[i][c];
        pk[c] = (unsigned)f2bf(u0) | ((unsigned)f2bf(u1) << 16);
      }
      unsigned* dst = (unsigned*)(U01 + ((size_t)(t*62 + n)*2048 + b)*32);
      #pragma unroll
      for (int c = 0; c < 5; ++c) dst[c0 + c] = pk[c];
      dst[10 + ch*3] = 0; dst[11 + ch*3] = 0; dst[12 + ch*3] = 0;
    }
  }
}

// ---------------------------------------------------------------------------
// k_gru: pipelined fused step, ONE barrier per step.
// At step t: prefetch U/w2 (t+2, global->reg), conv X_{t+1} (MFMA -> Xs[p^1]),
// gate GEMM_t (Xs[p],Hh[p],Hl[p]), gate VALU -> Hh/Hl[p^1].
// X/H tiles 32x64 u16, chunk-XOR-swizzled: slot = (chunk ^ ((row>>2)&3)).
// ---------------------------------------------------------------------------
__global__ __launch_bounds__(256, 3) void k_gru(
    const u16* __restrict__ U01, const u16* __restrict__ w2,
    const float* __restrict__ zz, const float* __restrict__ E,
    const float* __restrict__ bp,
    const u16* __restrict__ WihP, const u16* __restrict__ WhhP,
    const float* __restrict__ brz, const float* __restrict__ binv,
    const float* __restrict__ bhnv, float* __restrict__ outSum)
{
  __shared__ u16 Xs[2][32*64];
  __shared__ u16 Hh[2][32*64];
  __shared__ u16 Hl[2][32*64];
  __shared__ float zzs[8*32];
  __shared__ float red[128];

  const int tid = threadIdx.x;
  const int n_idx = blockIdx.x >> 6;
  const int b0 = (blockIdx.x & 63) << 5;
  const int lane = tid & 63;
  const int w_id = tid >> 6;
  const int ln = lane & 15;
  const int hi = lane >> 4;         // 0..3
  const int j = w_id*16 + ln;
  const int key = (ln >> 2) & 3;    // read-side swizzle key

  // persistent gate weight B-fragments
  s8v wihF[3][2], whhF[3][2];
  #pragma unroll
  for (int g = 0; g < 3; ++g)
    #pragma unroll
    for (int ks = 0; ks < 2; ++ks){
      int off = (g*64 + j)*64 + ks*32 + hi*8;
      wihF[g][ks] = *(const s8v*)(WihP + off);
      whhF[g][ks] = *(const s8v*)(WhhP + off);
    }
  const float bj_r  = brz[j];
  const float bj_z  = brz[64 + j];
  const float bj_in = binv[j];
  const float bj_hn = bhnv[j];
  float biasA[8];
  {
    float e0 = E[n_idx*3], e1 = E[n_idx*3+1], e2 = E[n_idx*3+2];
    #pragma unroll
    for (int t = 0; t < 8; ++t)
      biasA[t] = (j < 62) ? e0*bp[(t*3+0)*62 + j] + e1*bp[(t*3+1)*62 + j]
                          + e2*bp[(t*3+2)*62 + j] : 0.f;
  }
  { int t = tid >> 5, rw = tid & 31; zzs[tid] = zz[t*2048 + b0 + rw]; }
  for (int i = tid; i < 2048; i += 256){
    Hh[0][i] = 0; Hl[0][i] = 0; Hh[1][i] = 0; Hl[1][i] = 0;
  }

  auto load_u = [&](int t, s8v u[2]){
    #pragma unroll
    for (int mi = 0; mi < 2; ++mi)
      u[mi] = *(const s8v*)(U01 +
          ((size_t)(t*62 + n_idx)*2048 + b0 + mi*16 + ln)*32 + hi*8);
  };
  auto load_w = [&](int t){
    return *(const s8v*)(w2 + ((size_t)(t*62 + n_idx)*64 + j)*32 + hi*8);
  };
  auto conv = [&](int t, int pb, const s8v u[2], s8v wf, float bv){
    #pragma unroll
    for (int mi = 0; mi < 2; ++mi){
      f4v a;
      #pragma unroll
      for (int rg = 0; rg < 4; ++rg)
        a[rg] = zzs[t*32 + mi*16 + hi*4 + rg] * bv;
      a = __builtin_amdgcn_mfma_f32_16x16x32_bf16(u[mi], wf, a, 0,0,0);
      #pragma unroll
      for (int rg = 0; rg < 4; ++rg){
        int row = mi*16 + hi*4 + rg;
        Xs[pb][row*64 + (((j>>3) ^ hi)<<3) + (j&7)] = f2bf(a[rg]);
      }
    }
  };

  float h_reg[8];
  #pragma unroll
  for (int i = 0; i < 8; ++i) h_reg[i] = 0.f;

  __syncthreads();   // zzs + H-zero visible

  // prologue: X_0
  s8v uC[2]; load_u(0, uC); s8v wC = load_w(0);
  s8v uN[2]; load_u(1, uN); s8v wN = load_w(1);
  conv(0, 0, uC, wC, biasA[0]);
  __syncthreads();   // X_0 ready

  s8v uP[2]; s8v wP;
  #pragma unroll
  for (int t = 0; t < 8; ++t){
    const int pb = t & 1;
    if (t < 6){ load_u(t+2, uP); wP = load_w(t+2); }
    if (t < 7) conv(t+1, pb^1, uN, wN, biasA[t+1]);

    // ---- gate GEMM from buffers pb ----
    f4v ar[2], az[2], axn[2], ahn[2];
    #pragma unroll
    for (int mi = 0; mi < 2; ++mi){
      ar[mi] = (f4v){0.f,0.f,0.f,0.f};  az[mi] = (f4v){0.f,0.f,0.f,0.f};
      axn[mi] = (f4v){0.f,0.f,0.f,0.f}; ahn[mi] = (f4v){0.f,0.f,0.f,0.f};
    }
    #pragma unroll
    for (int ks = 0; ks < 2; ++ks)
      #pragma unroll
      for (int mi = 0; mi < 2; ++mi){
        int base = (mi*16 + ln)*64 + (((ks*4 + hi) ^ key) << 3);
        s8v xf = *(const s8v*)&Xs[pb][base];
        s8v hh = *(const s8v*)&Hh[pb][base];
        s8v hl = *(const s8v*)&Hl[pb][base];
        ar[mi]  = __builtin_amdgcn_mfma_f32_16x16x32_bf16(xf, wihF[0][ks], ar[mi], 0,0,0);
        az[mi]  = __builtin_amdgcn_mfma_f32_16x16x32_bf16(xf, wihF[1][ks], az[mi], 0,0,0);
        axn[mi] = __builtin_amdgcn_mfma_f32_16x16x32_bf16(xf, wihF[2][ks], axn[mi], 0,0,0);
        ar[mi]  = __builtin_amdgcn_mfma_f32_16x16x32_bf16(hh, whhF[0][ks], ar[mi], 0,0,0);
        az[mi]  = __builtin_amdgcn_mfma_f32_16x16x32_bf16(hh, whhF[1][ks], az[mi], 0,0,0);
        ahn[mi] = __builtin_amdgcn_mfma_f32_16x16x32_bf16(hh, whhF[2][ks], ahn[mi], 0,0,0);
        ar[mi]  = __builtin_amdgcn_mfma_f32_16x16x32_bf16(hl, whhF[0][ks], ar[mi], 0,0,0);
        az[mi]  = __builtin_amdgcn_mfma_f32_16x16x32_bf16(hl, whhF[1][ks], az[mi], 0,0,0);
        ahn[mi] = __builtin_amdgcn_mfma_f32_16x16x32_bf16(hl, whhF[2][ks], ahn[mi], 0,0,0);
      }

    // ---- gates + H update (write to pb^1) ----
    const bool last = (t == 7);
    #pragma unroll
    for (int mi = 0; mi < 2; ++mi)
      #pragma unroll
      for (int rg = 0; rg < 4; ++rg){
        float r  = sigmf(ar[mi][rg] + bj_r);
        float zg = sigmf(az[mi][rg] + bj_z);
        float ng = tanh_f(axn[mi][rg] + bj_in + r*(ahn[mi][rg] + bj_hn));
        int idx = mi*4 + rg;
        float hnew = ng + zg*(h_reg[idx] - ng);
        h_reg[idx] = hnew;
        if (!last){
          int row = mi*16 + hi*4 + rg;
          int wo = row*64 + (((j>>3) ^ hi)<<3) + (j&7);
          u16 hb = f2bf(hnew);
          Hh[pb^1][wo] = hb;
          Hl[pb^1][wo] = f2bf(hnew - bf2f(hb));
        }
      }
    if (t < 6){ uN[0] = uP[0]; uN[1] = uP[1]; wN = wP; }
    __syncthreads();   // X_{t+1}, H_{t+1} ready; frag reads of pb done
  }

  // ---- row-sum over hidden dim ----
  #pragma unroll
  for (int mi = 0; mi < 2; ++mi)
    #pragma unroll
    for (int rg = 0; rg < 4; ++rg){
      float v = h_reg[mi*4 + rg];
      v += __shfl_xor(v, 1); v += __shfl_xor(v, 2);
      v += __shfl_xor(v, 4); v += __shfl_xor(v, 8);
      if (ln == 0) red[w_id*32 + mi*16 + hi*4 + rg] = v;
    }
  __syncthreads();
  if (tid < 32)
    outSum[(size_t)n_idx*2048 + b0 + tid] =
        red[tid] + red[32+tid] + red[64+tid] + red[96+tid];
}

// ---------------------------------------------------------------------------
// k_mlp: 8 batches per block; W1 staged in LDS.
// ---------------------------------------------------------------------------
__global__ __launch_bounds__(256) void k_mlp(
    const float* __restrict__ outSum,
    const float* __restrict__ W1, const float* __restrict__ b1,
    const float* __restrict__ W2, const float* __restrict__ b2,
    float* __restrict__ out)
{
  const int b0 = blockIdx.x*8, tid = threadIdx.x;
  __shared__ float W1s[15872];    // 256 x 62
  __shared__ float vec[8][62];
  __shared__ float o1[8][256];
  for (int i = tid; i < 15872; i += 256) W1s[i] = W1[i];
  for (int i = tid; i < 496; i += 256){
    int n = i >> 3, bl = i & 7;
    vec[bl][n] = outSum[(size_t)n*2048 + b0 + bl];
  }
  __syncthreads();
  {
    float a[8];
    #pragma unroll
    for (int bl = 0; bl < 8; ++bl) a[bl] = b1[tid];
    for (int n = 0; n < 62; ++n){
      float w = W1s[tid*62 + n];
      #pragma unroll
      for (int bl = 0; bl < 8; ++bl) a[bl] += w * vec[bl][n];
    }
    #pragma unroll
    for (int bl = 0; bl < 8; ++bl) o1[bl][tid] = fmaxf(a[bl], 0.f);
  }
  __syncthreads();
  if (tid < 24){
    int bl = tid / 3, o = tid % 3;
    float s = b2[o];
    for (int k = 0; k < 256; ++k) s += o1[bl][k]*W2[o*256 + k];
    out[(b0+bl)*3 + o] = fmaxf(s, 0.f);
  }
}

// ---------------------------------------------------------------------------
extern "C" void kernel_launch(void* const* d_in, const int* in_sizes, int n_in,
                              void* d_out, int out_size, void* d_ws, size_t ws_size,
                              hipStream_t stream)
{
  const float* x   = (const float*)d_in[0];
  const float* PI  = (const float*)d_in[1];
  const float* E   = (const float*)d_in[2];
  const float* Wp  = (const float*)d_in[3];
  const float* bp  = (const float*)d_in[4];
  const float* Tp  = (const float*)d_in[5];
  const float* Wz  = (const float*)d_in[6];
  const float* Wih = (const float*)d_in[7];
  const float* Whh = (const float*)d_in[8];
  const float* bih = (const float*)d_in[9];
  const float* bhh = (const float*)d_in[10];
  const float* W1  = (const float*)d_in[11];
  const float* b1  = (const float*)d_in[12];
  const float* W2  = (const float*)d_in[13];
  const float* b2  = (const float*)d_in[14];
  float* out = (float*)d_out;

  char* ws = (char*)d_ws;
  size_t off = 0;
  auto take = [&](size_t bytes)->char*{
    char* p = ws + off; off = (off + bytes + 255) & ~(size_t)255; return p;
  };
  float* pA     = (float*)take(3844*4);
  float* palpha = (float*)take(72*4);
  float* pzz    = (float*)take(16384*4);
  u16*   pWihP  = (u16*)take(12288*2);
  u16*   pWhhP  = (u16*)take(12288*2);
  float* pbrz   = (float*)take(128*4);
  float* pbin   = (float*)take(64*4);
  float* pbhn   = (float*)take(64*4);
  u16*   pw2    = (u16*)take((size_t)1015808*2);
  u16*   pU01   = (u16*)take((size_t)32505856*2);
  float* pos    = (float*)take((size_t)126976*4);

  k_prep<<<1, 256, 0, stream>>>(E, Tp, Wih, Whh, bih, bhh,
                                pA, palpha, pWihP, pWhhP, pbrz, pbin, pbhn);
  k_w2<<<3968, 256, 0, stream>>>(E, Wp, pw2);
  k_zz<<<512, 256, 0, stream>>>(PI, Wz, pzz);
  k_u<<<2048, 256, 0, stream>>>(x, pA, palpha, pzz, pU01);
  k_gru<<<3968, 256, 0, stream>>>(pU01, pw2, pzz, E, bp, pWihP, pWhhP,
                                  pbrz, pbin, pbhn, pos);
  k_mlp<<<256, 256, 0, stream>>>(pos, W1, b1, W2, b2, out);
}

// Round 4
// 240.971 us; speedup vs baseline: 2.6471x; 1.1259x over previous
//
#include <hip/hip_runtime.h>

typedef unsigned short u16;
typedef _Float16 f16;
typedef __attribute__((ext_vector_type(8))) _Float16 h8v;
typedef __attribute__((ext_vector_type(4))) float f4v;

__device__ __forceinline__ u16 f2h_bits(float f){
  f16 h = (f16)f;
  return __builtin_bit_cast(u16, h);
}
__device__ __forceinline__ float sigmf(float x){
  return __builtin_amdgcn_rcpf(1.f + __expf(-x));
}
__device__ __forceinline__ float tanh_f(float x){
  return 1.f - 2.f*__builtin_amdgcn_rcpf(__expf(2.f*x) + 1.f);
}

// ---------------------------------------------------------------------------
// k_prep: A = softmax(relu(E E^T)), alpha = masked softmax(Tparam),
//         WhhH fp16 padded [3][64 col][64 k], gate bias vectors.
// ---------------------------------------------------------------------------
__global__ __launch_bounds__(256) void k_prep(
    const float* __restrict__ E, const float* __restrict__ Tp,
    const float* __restrict__ Whh,
    const float* __restrict__ bih, const float* __restrict__ bhh,
    float* __restrict__ A, float* __restrict__ alpha,
    u16* __restrict__ WhhH,
    float* __restrict__ brz, float* __restrict__ binv, float* __restrict__ bhnv)
{
  __shared__ float As[3844];
  const int tid = threadIdx.x;
  for (int i = tid; i < 3844; i += 256){
    int nn = i / 62, m = i % 62;
    float s = E[nn*3]*E[m*3] + E[nn*3+1]*E[m*3+1] + E[nn*3+2]*E[m*3+2];
    As[i] = s > 0.f ? s : 0.f;
  }
  __syncthreads();
  if (tid < 62){
    float mx = -1e30f;
    for (int m = 0; m < 62; ++m) mx = fmaxf(mx, As[tid*62+m]);
    float sum = 0.f;
    for (int m = 0; m < 62; ++m) sum += __expf(As[tid*62+m] - mx);
    float inv = 1.f / sum;
    for (int m = 0; m < 62; ++m) A[tid*62+m] = __expf(As[tid*62+m] - mx) * inv;
  }
  if (tid < 8){
    int t = tid;
    float mx = -1e30f;
    for (int s = 0; s <= t; ++s) mx = fmaxf(mx, Tp[t*9+s]);
    float sum = 0.f;
    for (int s = 0; s <= t; ++s) sum += __expf(Tp[t*9+s] - mx);
    float inv = 1.f / sum;
    for (int s = 0; s < 9; ++s)
      alpha[t*9+s] = (s <= t) ? __expf(Tp[t*9+s] - mx) * inv : 0.f;
  }
  for (int i = tid; i < 12288; i += 256){
    int row = i >> 6, k = i & 63, g = row >> 6, jj = row & 63;
    float vh = (jj < 62 && k < 62) ? Whh[(g*62+jj)*62 + k] : 0.f;
    WhhH[i] = f2h_bits(vh);
  }
  if (tid < 128){
    int g = tid >> 6, jj = tid & 63;
    brz[tid] = (jj < 62) ? bih[g*62+jj] + bhh[g*62+jj] : 0.f;
  }
  if (tid < 64){
    binv[tid] = (tid < 62) ? bih[124+tid] : 0.f;
    bhnv[tid] = (tid < 62) ? bhh[124+tid] : 0.f;
  }
}

// ---------------------------------------------------------------------------
// k_m2: per (t,n): w2[o][k20] = E@Wp; M2[col 0..191][k24] = Wih@w2 (fp16),
//       biasW[n][t][col] = (E@bp)@Wih^T.  col = g*64 + jj (g-padded).
// ---------------------------------------------------------------------------
__global__ __launch_bounds__(256) void k_m2(
    const float* __restrict__ E, const float* __restrict__ Wp,
    const float* __restrict__ bp, const float* __restrict__ Wih,
    u16* __restrict__ M2, float* __restrict__ biasW)
{
  const int bid = blockIdx.x;          // t*62+n
  const int t = bid / 62, n = bid % 62, tid = threadIdx.x;
  __shared__ float w2s[1240];          // [o][k20]
  __shared__ float bias[62];
  const float e0 = E[n*3], e1 = E[n*3+1], e2 = E[n*3+2];
  for (int i = tid; i < 1240; i += 256){
    int o = i / 20, k = i % 20, c = k >> 1, kl = k & 1;
    w2s[i] = e0*Wp[(((t*3+0)*2+kl)*10+c)*62 + o]
           + e1*Wp[(((t*3+1)*2+kl)*10+c)*62 + o]
           + e2*Wp[(((t*3+2)*2+kl)*10+c)*62 + o];
  }
  if (tid < 62)
    bias[tid] = e0*bp[(t*3+0)*62+tid] + e1*bp[(t*3+1)*62+tid]
              + e2*bp[(t*3+2)*62+tid];
  __syncthreads();
  for (int i = tid; i < 2304; i += 256){   // 192 cols x 12 dwords
    int col = i / 12, d = i % 12, g = col >> 6, jj = col & 63;
    unsigned outw = 0;
    if (jj < 62){
      int k0 = 2*d, k1 = 2*d + 1;
      float v0 = 0.f, v1 = 0.f;
      if (k0 < 20){
        const float* wr = Wih + (g*62+jj)*62;
        for (int o = 0; o < 62; ++o){
          float w = wr[o];
          v0 += w * w2s[o*20 + k0];
          v1 += w * w2s[o*20 + k1];
        }
      }
      outw = (unsigned)f2h_bits(v0) | ((unsigned)f2h_bits(v1) << 16);
    }
    ((unsigned*)M2)[((size_t)bid*192 + col)*12 + d] = outw;
  }
  if (tid < 192){
    int col = tid, g = col >> 6, jj = col & 63;
    float v = 0.f;
    if (jj < 62){
      const float* wr = Wih + (g*62+jj)*62;
      for (int o = 0; o < 62; ++o) v += wr[o]*bias[o];
    }
    biasW[((size_t)n*8 + t)*192 + col] = v;
  }
}

// ---------------------------------------------------------------------------
// k_zz: 4 batches/block, float4; zz[t][b] = sigmoid(sum_p PI[b,p]*Wz[t,p])
// ---------------------------------------------------------------------------
__global__ __launch_bounds__(256) void k_zz(
    const float* __restrict__ PI, const float* __restrict__ Wz,
    float* __restrict__ zzO)
{
  const int b0 = blockIdx.x*4, tid = threadIdx.x;
  float acc[32];
  #pragma unroll
  for (int i = 0; i < 32; ++i) acc[i] = 0.f;
  const float4* p0 = (const float4*)(PI + (size_t)(b0+0)*10000);
  const float4* p1 = (const float4*)(PI + (size_t)(b0+1)*10000);
  const float4* p2 = (const float4*)(PI + (size_t)(b0+2)*10000);
  const float4* p3 = (const float4*)(PI + (size_t)(b0+3)*10000);
  const float4* wz4 = (const float4*)Wz;
  for (int p = tid; p < 2500; p += 256){
    float4 x0 = p0[p], x1 = p1[p], x2 = p2[p], x3 = p3[p];
    #pragma unroll
    for (int t = 0; t < 8; ++t){
      float4 w = wz4[t*2500 + p];
      acc[t*4+0] += x0.x*w.x + x0.y*w.y + x0.z*w.z + x0.w*w.w;
      acc[t*4+1] += x1.x*w.x + x1.y*w.y + x1.z*w.z + x1.w*w.w;
      acc[t*4+2] += x2.x*w.x + x2.y*w.y + x2.z*w.z + x2.w*w.w;
      acc[t*4+3] += x3.x*w.x + x3.y*w.y + x3.z*w.z + x3.w*w.w;
    }
  }
  __shared__ float red[128];
  int lane = tid & 63, wid = tid >> 6;
  #pragma unroll
  for (int i = 0; i < 32; ++i){
    float v = acc[i];
    v += __shfl_xor(v, 1);  v += __shfl_xor(v, 2);  v += __shfl_xor(v, 4);
    v += __shfl_xor(v, 8);  v += __shfl_xor(v, 16); v += __shfl_xor(v, 32);
    if (lane == 0) red[i*4 + wid] = v;
  }
  __syncthreads();
  if (tid < 32){
    float s = red[tid*4] + red[tid*4+1] + red[tid*4+2] + red[tid*4+3];
    int t = tid >> 2, bq = tid & 3;
    zzO[t*2048 + b0 + bq] = sigmf(s);
  }
}

// ---------------------------------------------------------------------------
// k_u: per batch b; writes packed fp16 U01[((t*62+n)*2048+b)*24 + k],
//      k = 2c+part (0=U0,1=U1), k=20..23 zero pad.
// ---------------------------------------------------------------------------
__global__ __launch_bounds__(256) void k_u(
    const float* __restrict__ x, const float* __restrict__ A,
    const float* __restrict__ alpha, const float* __restrict__ zz,
    u16* __restrict__ U01)
{
  const int b = blockIdx.x, tid = threadIdx.x;
  __shared__ float xs[5580];      // [s][n][c]
  __shared__ float As[3844];
  __shared__ float al[72];
  __shared__ float zzb[8];
  const float4* px = (const float4*)(x + (size_t)b*5580);
  for (int i = tid; i < 1395; i += 256) ((float4*)xs)[i] = px[i];
  for (int i = tid; i < 961; i += 256) ((float4*)As)[i] = ((const float4*)A)[i];
  if (tid < 72) al[tid] = alpha[tid];
  if (tid < 8) zzb[tid] = zz[tid*2048 + b];
  __syncthreads();

  const int t = tid >> 5, nq = (tid >> 1) & 15, ch = tid & 1;
  const int n0 = nq*4, c0 = ch*5;
  float acc[4][5];
  #pragma unroll
  for (int i = 0; i < 4; ++i)
    #pragma unroll
    for (int c = 0; c < 5; ++c) acc[i][c] = 0.f;
  for (int m = 0; m < 62; ++m){
    float xv[5];
    #pragma unroll
    for (int c = 0; c < 5; ++c) xv[c] = xs[(t+1)*620 + m*10 + c0 + c];
    #pragma unroll
    for (int i = 0; i < 4; ++i){
      int n = n0 + i;
      float a = (n < 62) ? As[n*62 + m] : 0.f;
      #pragma unroll
      for (int c = 0; c < 5; ++c) acc[i][c] += a*xv[c];
    }
  }
  float alr[9];
  #pragma unroll
  for (int s = 0; s < 9; ++s) alr[s] = al[t*9+s];
  float z = zzb[t];
  #pragma unroll
  for (int i = 0; i < 4; ++i){
    int n = n0 + i;
    if (n < 62){
      unsigned pk[5];
      #pragma unroll
      for (int c = 0; c < 5; ++c){
        int cc = c0 + c;
        float xw = 0.f;
        #pragma unroll
        for (int s = 0; s < 9; ++s) xw += alr[s]*xs[s*620 + n*10 + cc];
        float u0 = z*xs[(t+1)*620 + n*10 + cc] + xw;
        float u1 = z*acc[i][c];
        pk[c] = (unsigned)f2h_bits(u0) | ((unsigned)f2h_bits(u1) << 16);
      }
      unsigned* dst = (unsigned*)(U01 + ((size_t)(t*62 + n)*2048 + b)*24);
      #pragma unroll
      for (int c = 0; c < 5; ++c) dst[c0 + c] = pk[c];
      dst[10 + ch] = 0;
    }
  }
}

// ---------------------------------------------------------------------------
// k_gru: gi = U@M2 + zz*biasW (regs), gh = H@WhhH (LDS, stride 72), 1 bar/step.
// Block = (n, 32-batch tile), 4 waves; XCD-bijective bid remap.
// ---------------------------------------------------------------------------
__global__ __launch_bounds__(256) void k_gru(
    const u16* __restrict__ U01, const u16* __restrict__ M2,
    const float* __restrict__ zz, const float* __restrict__ biasW,
    const u16* __restrict__ WhhH,
    const float* __restrict__ brz, const float* __restrict__ binv,
    const float* __restrict__ bhnv, float* __restrict__ outSum)
{
  __shared__ f16 Hs[2][32*72];
  __shared__ float biasWs[1536];   // [t][192]
  __shared__ float zzs[256];       // [t][32]
  __shared__ float red[128];

  const int tid = threadIdx.x;
  int bid = blockIdx.x;
  bid = (bid & 7)*496 + (bid >> 3);     // same-n blocks -> same XCD
  const int n_idx = bid >> 6;
  const int b0 = (bid & 63) << 5;
  const int lane = tid & 63;
  const int w_id = tid >> 6;
  const int ln = lane & 15;
  const int hi = lane >> 4;
  const int j = w_id*16 + ln;

  // persistent Whh B-fragments (fp16)
  h8v whhF[3][2];
  #pragma unroll
  for (int g = 0; g < 3; ++g)
    #pragma unroll
    for (int ks = 0; ks < 2; ++ks)
      whhF[g][ks] = *(const h8v*)(const void*)(WhhH + (g*64 + j)*64 + ks*32 + hi*8);

  const float bj_r  = brz[j];
  const float bj_z  = brz[64 + j];
  const float bj_in = binv[j];
  const float bj_hn = bhnv[j];

  for (int i = tid; i < 1536; i += 256)
    biasWs[i] = biasW[(size_t)n_idx*1536 + i];
  { int t = tid >> 5, rw = tid & 31; zzs[tid] = zz[t*2048 + b0 + rw]; }
  for (int i = tid; i < 2304; i += 256) Hs[0][i] = (f16)0.f;

  auto ldU = [&](int t, int mi)->h8v{
    if (hi == 3) return (h8v){};
    return *(const h8v*)(const void*)(U01 +
        ((size_t)(t*62 + n_idx)*2048 + b0 + mi*16 + ln)*24 + hi*8);
  };
  auto ldM = [&](int t, int g)->h8v{
    if (hi == 3) return (h8v){};
    return *(const h8v*)(const void*)(M2 +
        ((size_t)(t*62 + n_idx)*192 + g*64 + j)*24 + hi*8);
  };

  h8v uF[3][2], mF[2][3];
  uF[0][0] = ldU(0,0); uF[0][1] = ldU(0,1);
  uF[1][0] = ldU(1,0); uF[1][1] = ldU(1,1);
  mF[0][0] = ldM(0,0); mF[0][1] = ldM(0,1); mF[0][2] = ldM(0,2);

  float h_reg[8];
  #pragma unroll
  for (int i = 0; i < 8; ++i) h_reg[i] = 0.f;
  __syncthreads();

  #pragma unroll
  for (int t = 0; t < 8; ++t){
    const int p = t & 1, su = t % 3, sm = t & 1;
    if (t < 6){ uF[(t+2)%3][0] = ldU(t+2,0); uF[(t+2)%3][1] = ldU(t+2,1); }
    if (t < 7){
      mF[(t+1)&1][0] = ldM(t+1,0);
      mF[(t+1)&1][1] = ldM(t+1,1);
      mF[(t+1)&1][2] = ldM(t+1,2);
    }
    const float bw_r = biasWs[t*192 + j];
    const float bw_z = biasWs[t*192 + 64 + j];
    const float bw_n = biasWs[t*192 + 128 + j];

    f4v ar[2], az[2], axn[2], ahn[2];
    #pragma unroll
    for (int mi = 0; mi < 2; ++mi){
      f4v zv = *(const f4v*)&zzs[t*32 + mi*16 + hi*4];
      #pragma unroll
      for (int rg = 0; rg < 4; ++rg){
        ar[mi][rg]  = zv[rg]*bw_r;
        az[mi][rg]  = zv[rg]*bw_z;
        axn[mi][rg] = zv[rg]*bw_n;
        ahn[mi][rg] = 0.f;
      }
      ar[mi]  = __builtin_amdgcn_mfma_f32_16x16x32_f16(uF[su][mi], mF[sm][0], ar[mi], 0,0,0);
      az[mi]  = __builtin_amdgcn_mfma_f32_16x16x32_f16(uF[su][mi], mF[sm][1], az[mi], 0,0,0);
      axn[mi] = __builtin_amdgcn_mfma_f32_16x16x32_f16(uF[su][mi], mF[sm][2], axn[mi], 0,0,0);
      #pragma unroll
      for (int ks = 0; ks < 2; ++ks){
        h8v hf = *(const h8v*)&Hs[p][(mi*16 + ln)*72 + ks*32 + hi*8];
        ar[mi]  = __builtin_amdgcn_mfma_f32_16x16x32_f16(hf, whhF[0][ks], ar[mi], 0,0,0);
        az[mi]  = __builtin_amdgcn_mfma_f32_16x16x32_f16(hf, whhF[1][ks], az[mi], 0,0,0);
        ahn[mi] = __builtin_amdgcn_mfma_f32_16x16x32_f16(hf, whhF[2][ks], ahn[mi], 0,0,0);
      }
    }
    #pragma unroll
    for (int mi = 0; mi < 2; ++mi)
      #pragma unroll
      for (int rg = 0; rg < 4; ++rg){
        float r  = sigmf(ar[mi][rg] + bj_r);
        float zg = sigmf(az[mi][rg] + bj_z);
        float ng = tanh_f(axn[mi][rg] + bj_in + r*(ahn[mi][rg] + bj_hn));
        int idx = mi*4 + rg;
        float hnew = ng + zg*(h_reg[idx] - ng);
        h_reg[idx] = hnew;
        if (t < 7) Hs[p^1][(mi*16 + hi*4 + rg)*72 + j] = (f16)hnew;
      }
    __syncthreads();
  }

  // ---- row-sum over hidden dim ----
  #pragma unroll
  for (int mi = 0; mi < 2; ++mi)
    #pragma unroll
    for (int rg = 0; rg < 4; ++rg){
      float v = h_reg[mi*4 + rg];
      v += __shfl_xor(v, 1); v += __shfl_xor(v, 2);
      v += __shfl_xor(v, 4); v += __shfl_xor(v, 8);
      if (ln == 0) red[w_id*32 + mi*16 + hi*4 + rg] = v;
    }
  __syncthreads();
  if (tid < 32)
    outSum[(size_t)n_idx*2048 + b0 + tid] =
        red[tid] + red[32+tid] + red[64+tid] + red[96+tid];
}

// ---------------------------------------------------------------------------
// k_mlp: 8 batches per block; W1 staged in LDS.
// ---------------------------------------------------------------------------
__global__ __launch_bounds__(256) void k_mlp(
    const float* __restrict__ outSum,
    const float* __restrict__ W1, const float* __restrict__ b1,
    const float* __restrict__ W2, const float* __restrict__ b2,
    float* __restrict__ out)
{
  const int b0 = blockIdx.x*8, tid = threadIdx.x;
  __shared__ float W1s[15872];    // 256 x 62
  __shared__ float vec[8][62];
  __shared__ float o1[8][256];
  for (int i = tid; i < 15872; i += 256) W1s[i] = W1[i];
  for (int i = tid; i < 496; i += 256){
    int n = i >> 3, bl = i & 7;
    vec[bl][n] = outSum[(size_t)n*2048 + b0 + bl];
  }
  __syncthreads();
  {
    float a[8];
    #pragma unroll
    for (int bl = 0; bl < 8; ++bl) a[bl] = b1[tid];
    for (int n = 0; n < 62; ++n){
      float w = W1s[tid*62 + n];
      #pragma unroll
      for (int bl = 0; bl < 8; ++bl) a[bl] += w * vec[bl][n];
    }
    #pragma unroll
    for (int bl = 0; bl < 8; ++bl) o1[bl][tid] = fmaxf(a[bl], 0.f);
  }
  __syncthreads();
  if (tid < 24){
    int bl = tid / 3, o = tid % 3;
    float s = b2[o];
    for (int k = 0; k < 256; ++k) s += o1[bl][k]*W2[o*256 + k];
    out[(b0+bl)*3 + o] = fmaxf(s, 0.f);
  }
}

// ---------------------------------------------------------------------------
extern "C" void kernel_launch(void* const* d_in, const int* in_sizes, int n_in,
                              void* d_out, int out_size, void* d_ws, size_t ws_size,
                              hipStream_t stream)
{
  const float* x   = (const float*)d_in[0];
  const float* PI  = (const float*)d_in[1];
  const float* E   = (const float*)d_in[2];
  const float* Wp  = (const float*)d_in[3];
  const float* bp  = (const float*)d_in[4];
  const float* Tp  = (const float*)d_in[5];
  const float* Wz  = (const float*)d_in[6];
  const float* Wih = (const float*)d_in[7];
  const float* Whh = (const float*)d_in[8];
  const float* bih = (const float*)d_in[9];
  const float* bhh = (const float*)d_in[10];
  const float* W1  = (const float*)d_in[11];
  const float* b1  = (const float*)d_in[12];
  const float* W2  = (const float*)d_in[13];
  const float* b2  = (const float*)d_in[14];
  float* out = (float*)d_out;

  char* ws = (char*)d_ws;
  size_t off = 0;
  auto take = [&](size_t bytes)->char*{
    char* p = ws + off; off = (off + bytes + 255) & ~(size_t)255; return p;
  };
  float* pA     = (float*)take(3844*4);
  float* palpha = (float*)take(72*4);
  float* pzz    = (float*)take(16384*4);
  u16*   pWhhH  = (u16*)take(12288*2);
  float* pbrz   = (float*)take(128*4);
  float* pbin   = (float*)take(64*4);
  float* pbhn   = (float*)take(64*4);
  u16*   pM2    = (u16*)take((size_t)496*192*24*2);
  float* pbiasW = (float*)take((size_t)62*8*192*4);
  u16*   pU01   = (u16*)take((size_t)496*2048*24*2);
  float* pos    = (float*)take((size_t)126976*4);

  k_prep<<<1, 256, 0, stream>>>(E, Tp, Whh, bih, bhh,
                                pA, palpha, pWhhH, pbrz, pbin, pbhn);
  k_m2<<<496, 256, 0, stream>>>(E, Wp, bp, Wih, pM2, pbiasW);
  k_zz<<<512, 256, 0, stream>>>(PI, Wz, pzz);
  k_u<<<2048, 256, 0, stream>>>(x, pA, palpha, pzz, pU01);
  k_gru<<<3968, 256, 0, stream>>>(pU01, pM2, pzz, pbiasW, pWhhH,
                                  pbrz, pbin, pbhn, pos);
  k_mlp<<<256, 256, 0, stream>>>(pos, W1, b1, W2, b2, out);
}

// Round 5
// 232.552 us; speedup vs baseline: 2.7430x; 1.0362x over previous
//
#include <hip/hip_runtime.h>

typedef unsigned short u16;
typedef _Float16 f16;
typedef __attribute__((ext_vector_type(8))) _Float16 h8v;
typedef __attribute__((ext_vector_type(4))) float f4v;

__device__ __forceinline__ u16 f2h_bits(float f){
  f16 h = (f16)f;
  return __builtin_bit_cast(u16, h);
}
__device__ __forceinline__ float sigmf(float x){
  return __builtin_amdgcn_rcpf(1.f + __expf(-x));
}
__device__ __forceinline__ float tanh_f(float x){
  return 1.f - 2.f*__builtin_amdgcn_rcpf(__expf(2.f*x) + 1.f);
}

// ---------------------------------------------------------------------------
// k_prep: A = softmax(relu(E E^T)), alpha = masked softmax(Tparam),
//         WhhH fp16 [3 gates][64 col][64 k]; k=62 row carries gate biases
//         (homogeneous-coordinate trick: H[k=62] == 1.0).
// ---------------------------------------------------------------------------
__global__ __launch_bounds__(256) void k_prep(
    const float* __restrict__ E, const float* __restrict__ Tp,
    const float* __restrict__ Whh,
    const float* __restrict__ bih, const float* __restrict__ bhh,
    float* __restrict__ A, float* __restrict__ alpha,
    u16* __restrict__ WhhH)
{
  __shared__ float As[3844];
  const int tid = threadIdx.x;
  for (int i = tid; i < 3844; i += 256){
    int nn = i / 62, m = i % 62;
    float s = E[nn*3]*E[m*3] + E[nn*3+1]*E[m*3+1] + E[nn*3+2]*E[m*3+2];
    As[i] = s > 0.f ? s : 0.f;
  }
  __syncthreads();
  if (tid < 62){
    float mx = -1e30f;
    for (int m = 0; m < 62; ++m) mx = fmaxf(mx, As[tid*62+m]);
    float sum = 0.f;
    for (int m = 0; m < 62; ++m) sum += __expf(As[tid*62+m] - mx);
    float inv = 1.f / sum;
    for (int m = 0; m < 62; ++m) A[tid*62+m] = __expf(As[tid*62+m] - mx) * inv;
  }
  if (tid < 8){
    int t = tid;
    float mx = -1e30f;
    for (int s = 0; s <= t; ++s) mx = fmaxf(mx, Tp[t*9+s]);
    float sum = 0.f;
    for (int s = 0; s <= t; ++s) sum += __expf(Tp[t*9+s] - mx);
    float inv = 1.f / sum;
    for (int s = 0; s < 9; ++s)
      alpha[t*9+s] = (s <= t) ? __expf(Tp[t*9+s] - mx) * inv : 0.f;
  }
  for (int i = tid; i < 12288; i += 256){
    int row = i >> 6, k = i & 63, g = row >> 6, jj = row & 63;
    float vh = 0.f;
    if (jj < 62){
      if (k < 62) vh = Whh[(g*62+jj)*62 + k];
      else if (k == 62) vh = (g < 2) ? (bih[g*62+jj] + bhh[g*62+jj]) : bhh[124+jj];
    }
    WhhH[i] = f2h_bits(vh);
  }
}

// ---------------------------------------------------------------------------
// k_m2: per (t,n): w2[o][k20] = E@Wp; M2[col][k24] = Wih@w2 (fp16),
//       plus affine rows: k=20 -> biasW = (E@bp)@Wih^T, k=21 -> b_ih(n-gate),
//       k=22..23 -> 0.  col = g*64 + jj (g-padded).
// ---------------------------------------------------------------------------
__global__ __launch_bounds__(256) void k_m2(
    const float* __restrict__ E, const float* __restrict__ Wp,
    const float* __restrict__ bp, const float* __restrict__ Wih,
    const float* __restrict__ bih, u16* __restrict__ M2)
{
  const int bid = blockIdx.x;          // t*62+n
  const int t = bid / 62, n = bid % 62, tid = threadIdx.x;
  __shared__ float w2s[1240];          // [o][k20]
  __shared__ float bias[62];
  const float e0 = E[n*3], e1 = E[n*3+1], e2 = E[n*3+2];
  for (int i = tid; i < 1240; i += 256){
    int o = i / 20, k = i % 20, c = k >> 1, kl = k & 1;
    w2s[i] = e0*Wp[(((t*3+0)*2+kl)*10+c)*62 + o]
           + e1*Wp[(((t*3+1)*2+kl)*10+c)*62 + o]
           + e2*Wp[(((t*3+2)*2+kl)*10+c)*62 + o];
  }
  if (tid < 62)
    bias[tid] = e0*bp[(t*3+0)*62+tid] + e1*bp[(t*3+1)*62+tid]
              + e2*bp[(t*3+2)*62+tid];
  __syncthreads();
  for (int i = tid; i < 2304; i += 256){   // 192 cols x 12 dwords
    int col = i / 12, d = i % 12, g = col >> 6, jj = col & 63;
    unsigned outw = 0;
    if (jj < 62){
      const float* wr = Wih + (g*62+jj)*62;
      if (d < 10){
        int k0 = 2*d;
        float v0 = 0.f, v1 = 0.f;
        for (int o = 0; o < 62; ++o){
          float w = wr[o];
          v0 += w * w2s[o*20 + k0];
          v1 += w * w2s[o*20 + k0 + 1];
        }
        outw = (unsigned)f2h_bits(v0) | ((unsigned)f2h_bits(v1) << 16);
      } else if (d == 10){
        float v0 = 0.f;
        for (int o = 0; o < 62; ++o) v0 += wr[o]*bias[o];
        float v1 = (g == 2) ? bih[124+jj] : 0.f;
        outw = (unsigned)f2h_bits(v0) | ((unsigned)f2h_bits(v1) << 16);
      }
    }
    ((unsigned*)M2)[((size_t)bid*192 + col)*12 + d] = outw;
  }
}

// ---------------------------------------------------------------------------
// k_zz: 4 batches/block, float4; zz[t][b] = sigmoid(sum_p PI[b,p]*Wz[t,p])
// ---------------------------------------------------------------------------
__global__ __launch_bounds__(256) void k_zz(
    const float* __restrict__ PI, const float* __restrict__ Wz,
    float* __restrict__ zzO)
{
  const int b0 = blockIdx.x*4, tid = threadIdx.x;
  float acc[32];
  #pragma unroll
  for (int i = 0; i < 32; ++i) acc[i] = 0.f;
  const float4* p0 = (const float4*)(PI + (size_t)(b0+0)*10000);
  const float4* p1 = (const float4*)(PI + (size_t)(b0+1)*10000);
  const float4* p2 = (const float4*)(PI + (size_t)(b0+2)*10000);
  const float4* p3 = (const float4*)(PI + (size_t)(b0+3)*10000);
  const float4* wz4 = (const float4*)Wz;
  for (int p = tid; p < 2500; p += 256){
    float4 x0 = p0[p], x1 = p1[p], x2 = p2[p], x3 = p3[p];
    #pragma unroll
    for (int t = 0; t < 8; ++t){
      float4 w = wz4[t*2500 + p];
      acc[t*4+0] += x0.x*w.x + x0.y*w.y + x0.z*w.z + x0.w*w.w;
      acc[t*4+1] += x1.x*w.x + x1.y*w.y + x1.z*w.z + x1.w*w.w;
      acc[t*4+2] += x2.x*w.x + x2.y*w.y + x2.z*w.z + x2.w*w.w;
      acc[t*4+3] += x3.x*w.x + x3.y*w.y + x3.z*w.z + x3.w*w.w;
    }
  }
  __shared__ float red[128];
  int lane = tid & 63, wid = tid >> 6;
  #pragma unroll
  for (int i = 0; i < 32; ++i){
    float v = acc[i];
    v += __shfl_xor(v, 1);  v += __shfl_xor(v, 2);  v += __shfl_xor(v, 4);
    v += __shfl_xor(v, 8);  v += __shfl_xor(v, 16); v += __shfl_xor(v, 32);
    if (lane == 0) red[i*4 + wid] = v;
  }
  __syncthreads();
  if (tid < 32){
    float s = red[tid*4] + red[tid*4+1] + red[tid*4+2] + red[tid*4+3];
    int t = tid >> 2, bq = tid & 3;
    zzO[t*2048 + b0 + bq] = sigmf(s);
  }
}

// ---------------------------------------------------------------------------
// k_u: per batch b; writes packed fp16 U01[((t*62+n)*2048+b)*24 + k]:
//      k=2c+part (0=U0,1=U1) for c<10; k=20 -> zz; k=21 -> 1.0; k=22,23 -> 0.
// ---------------------------------------------------------------------------
__global__ __launch_bounds__(256) void k_u(
    const float* __restrict__ x, const float* __restrict__ A,
    const float* __restrict__ alpha, const float* __restrict__ zz,
    u16* __restrict__ U01)
{
  const int b = blockIdx.x, tid = threadIdx.x;
  __shared__ float xs[5580];      // [s][n][c]
  __shared__ float As[3844];
  __shared__ float al[72];
  __shared__ float zzb[8];
  const float4* px = (const float4*)(x + (size_t)b*5580);
  for (int i = tid; i < 1395; i += 256) ((float4*)xs)[i] = px[i];
  for (int i = tid; i < 961; i += 256) ((float4*)As)[i] = ((const float4*)A)[i];
  if (tid < 72) al[tid] = alpha[tid];
  if (tid < 8) zzb[tid] = zz[tid*2048 + b];
  __syncthreads();

  const int t = tid >> 5, nq = (tid >> 1) & 15, ch = tid & 1;
  const int n0 = nq*4, c0 = ch*5;
  float acc[4][5];
  #pragma unroll
  for (int i = 0; i < 4; ++i)
    #pragma unroll
    for (int c = 0; c < 5; ++c) acc[i][c] = 0.f;
  for (int m = 0; m < 62; ++m){
    float xv[5];
    #pragma unroll
    for (int c = 0; c < 5; ++c) xv[c] = xs[(t+1)*620 + m*10 + c0 + c];
    #pragma unroll
    for (int i = 0; i < 4; ++i){
      int n = n0 + i;
      float a = (n < 62) ? As[n*62 + m] : 0.f;
      #pragma unroll
      for (int c = 0; c < 5; ++c) acc[i][c] += a*xv[c];
    }
  }
  float alr[9];
  #pragma unroll
  for (int s = 0; s < 9; ++s) alr[s] = al[t*9+s];
  float z = zzb[t];
  unsigned zpack = (unsigned)f2h_bits(z) | (0x3C00u << 16);  // [zz | 1.0]
  #pragma unroll
  for (int i = 0; i < 4; ++i){
    int n = n0 + i;
    if (n < 62){
      unsigned pk[5];
      #pragma unroll
      for (int c = 0; c < 5; ++c){
        int cc = c0 + c;
        float xw = 0.f;
        #pragma unroll
        for (int s = 0; s < 9; ++s) xw += alr[s]*xs[s*620 + n*10 + cc];
        float u0 = z*xs[(t+1)*620 + n*10 + cc] + xw;
        float u1 = z*acc[i][c];
        pk[c] = (unsigned)f2h_bits(u0) | ((unsigned)f2h_bits(u1) << 16);
      }
      unsigned* dst = (unsigned*)(U01 + ((size_t)(t*62 + n)*2048 + b)*24);
      #pragma unroll
      for (int c = 0; c < 5; ++c) dst[c0 + c] = pk[c];
      if (ch == 0) dst[10] = zpack; else dst[11] = 0;
    }
  }
}

// ---------------------------------------------------------------------------
// k_gru: all-affine-folded GRU step. gi = U@M2 (incl. zz*biasW + b_in),
//        gh = H@Whh (incl. gate biases via H[62]=1). 1 barrier/step.
//        Block = (n, 32-batch tile), 4 col-split waves.
// ---------------------------------------------------------------------------
__global__ __launch_bounds__(256, 3) void k_gru(
    const u16* __restrict__ U01, const u16* __restrict__ M2,
    const u16* __restrict__ WhhH, float* __restrict__ outSum)
{
  __shared__ f16 Hs[2][32*72];     // stride 72: natural bank rotation
  __shared__ float red[128];

  const int tid = threadIdx.x;
  int bid = blockIdx.x;
  bid = (bid & 7)*496 + (bid >> 3);     // XCD-bijective: same-n -> same XCD
  const int n_idx = bid >> 6;
  const int b0 = (bid & 63) << 5;
  const int lane = tid & 63;
  const int w_id = tid >> 6;
  const int ln = lane & 15;
  const int hi = lane >> 4;
  const int j = w_id*16 + ln;           // this lane's gate column

  // persistent Whh B-fragments (48 VGPR)
  h8v whhF[3][2];
  #pragma unroll
  for (int g = 0; g < 3; ++g)
    #pragma unroll
    for (int ks = 0; ks < 2; ++ks)
      whhF[g][ks] = *(const h8v*)(const void*)(WhhH + (g*64 + j)*64 + ks*32 + hi*8);

  // init both H buffers: zeros, col 62 = 1.0 (homogeneous slot), col 63 = 0
  for (int i = tid; i < 2304; i += 256){
    f16 v = ((i % 72) == 62) ? (f16)1.f : (f16)0.f;
    Hs[0][i] = v; Hs[1][i] = v;
  }

  auto ldU = [&](int t, int mi)->h8v{
    if (hi == 3) return (h8v){};
    return *(const h8v*)(const void*)(U01 +
        ((size_t)(t*62 + n_idx)*2048 + b0 + mi*16 + ln)*24 + hi*8);
  };
  auto ldM = [&](int t, int g)->h8v{
    if (hi == 3) return (h8v){};
    return *(const h8v*)(const void*)(M2 +
        ((size_t)(t*62 + n_idx)*192 + g*64 + j)*24 + hi*8);
  };

  h8v uA0 = ldU(0,0), uA1 = ldU(0,1);
  h8v uB0, uB1;

  float h_reg[8];
  #pragma unroll
  for (int i = 0; i < 8; ++i) h_reg[i] = 0.f;
  __syncthreads();

  #pragma unroll
  for (int t = 0; t < 8; ++t){
    const int p = t & 1;
    // M2 fragments: issued now, consumed after the gh phase (in-step hiding)
    h8v mf0 = ldM(t,0), mf1 = ldM(t,1), mf2 = ldM(t,2);
    if (t < 7){ uB0 = ldU(t+1,0); uB1 = ldU(t+1,1); }

    f4v ar[2], az[2], axn[2], ahn[2];
    #pragma unroll
    for (int mi = 0; mi < 2; ++mi){
      ar[mi] = (f4v){0.f,0.f,0.f,0.f};  az[mi] = (f4v){0.f,0.f,0.f,0.f};
      axn[mi] = (f4v){0.f,0.f,0.f,0.f}; ahn[mi] = (f4v){0.f,0.f,0.f,0.f};
    }
    // gh phase: H (incl. bias row 62) x Whh
    #pragma unroll
    for (int ks = 0; ks < 2; ++ks)
      #pragma unroll
      for (int mi = 0; mi < 2; ++mi){
        h8v hf = *(const h8v*)&Hs[p][(mi*16 + ln)*72 + ks*32 + hi*8];
        ar[mi]  = __builtin_amdgcn_mfma_f32_16x16x32_f16(hf, whhF[0][ks], ar[mi], 0,0,0);
        az[mi]  = __builtin_amdgcn_mfma_f32_16x16x32_f16(hf, whhF[1][ks], az[mi], 0,0,0);
        ahn[mi] = __builtin_amdgcn_mfma_f32_16x16x32_f16(hf, whhF[2][ks], ahn[mi], 0,0,0);
      }
    // gi phase: U (incl. zz, 1.0 slots) x M2
    ar[0]  = __builtin_amdgcn_mfma_f32_16x16x32_f16(uA0, mf0, ar[0], 0,0,0);
    ar[1]  = __builtin_amdgcn_mfma_f32_16x16x32_f16(uA1, mf0, ar[1], 0,0,0);
    az[0]  = __builtin_amdgcn_mfma_f32_16x16x32_f16(uA0, mf1, az[0], 0,0,0);
    az[1]  = __builtin_amdgcn_mfma_f32_16x16x32_f16(uA1, mf1, az[1], 0,0,0);
    axn[0] = __builtin_amdgcn_mfma_f32_16x16x32_f16(uA0, mf2, axn[0], 0,0,0);
    axn[1] = __builtin_amdgcn_mfma_f32_16x16x32_f16(uA1, mf2, axn[1], 0,0,0);

    // gates (bias-free)
    const bool last = (t == 7);
    #pragma unroll
    for (int mi = 0; mi < 2; ++mi)
      #pragma unroll
      for (int rg = 0; rg < 4; ++rg){
        float r  = sigmf(ar[mi][rg]);
        float zg = sigmf(az[mi][rg]);
        float ng = tanh_f(axn[mi][rg] + r*ahn[mi][rg]);
        int idx = mi*4 + rg;
        float hnew = ng + zg*(h_reg[idx] - ng);
        h_reg[idx] = hnew;
        if (!last && j < 62)
          Hs[p^1][(mi*16 + hi*4 + rg)*72 + j] = (f16)hnew;
      }
    uA0 = uB0; uA1 = uB1;
    __syncthreads();
  }

  // ---- row-sum over hidden dim (mask pad cols 62,63) ----
  #pragma unroll
  for (int mi = 0; mi < 2; ++mi)
    #pragma unroll
    for (int rg = 0; rg < 4; ++rg){
      float v = (j < 62) ? h_reg[mi*4 + rg] : 0.f;
      v += __shfl_xor(v, 1); v += __shfl_xor(v, 2);
      v += __shfl_xor(v, 4); v += __shfl_xor(v, 8);
      if (ln == 0) red[w_id*32 + mi*16 + hi*4 + rg] = v;
    }
  __syncthreads();
  if (tid < 32)
    outSum[(size_t)n_idx*2048 + b0 + tid] =
        red[tid] + red[32+tid] + red[64+tid] + red[96+tid];
}

// ---------------------------------------------------------------------------
// k_mlp: 8 batches per block; W1 staged in LDS.
// ---------------------------------------------------------------------------
__global__ __launch_bounds__(256) void k_mlp(
    const float* __restrict__ outSum,
    const float* __restrict__ W1, const float* __restrict__ b1,
    const float* __restrict__ W2, const float* __restrict__ b2,
    float* __restrict__ out)
{
  const int b0 = blockIdx.x*8, tid = threadIdx.x;
  __shared__ float W1s[15872];    // 256 x 62
  __shared__ float vec[8][62];
  __shared__ float o1[8][256];
  for (int i = tid; i < 15872; i += 256) W1s[i] = W1[i];
  for (int i = tid; i < 496; i += 256){
    int n = i >> 3, bl = i & 7;
    vec[bl][n] = outSum[(size_t)n*2048 + b0 + bl];
  }
  __syncthreads();
  {
    float a[8];
    #pragma unroll
    for (int bl = 0; bl < 8; ++bl) a[bl] = b1[tid];
    for (int n = 0; n < 62; ++n){
      float w = W1s[tid*62 + n];
      #pragma unroll
      for (int bl = 0; bl < 8; ++bl) a[bl] += w * vec[bl][n];
    }
    #pragma unroll
    for (int bl = 0; bl < 8; ++bl) o1[bl][tid] = fmaxf(a[bl], 0.f);
  }
  __syncthreads();
  if (tid < 24){
    int bl = tid / 3, o = tid % 3;
    float s = b2[o];
    for (int k = 0; k < 256; ++k) s += o1[bl][k]*W2[o*256 + k];
    out[(b0+bl)*3 + o] = fmaxf(s, 0.f);
  }
}

// ---------------------------------------------------------------------------
extern "C" void kernel_launch(void* const* d_in, const int* in_sizes, int n_in,
                              void* d_out, int out_size, void* d_ws, size_t ws_size,
                              hipStream_t stream)
{
  const float* x   = (const float*)d_in[0];
  const float* PI  = (const float*)d_in[1];
  const float* E   = (const float*)d_in[2];
  const float* Wp  = (const float*)d_in[3];
  const float* bp  = (const float*)d_in[4];
  const float* Tp  = (const float*)d_in[5];
  const float* Wz  = (const float*)d_in[6];
  const float* Wih = (const float*)d_in[7];
  const float* Whh = (const float*)d_in[8];
  const float* bih = (const float*)d_in[9];
  const float* bhh = (const float*)d_in[10];
  const float* W1  = (const float*)d_in[11];
  const float* b1  = (const float*)d_in[12];
  const float* W2  = (const float*)d_in[13];
  const float* b2  = (const float*)d_in[14];
  float* out = (float*)d_out;

  char* ws = (char*)d_ws;
  size_t off = 0;
  auto take = [&](size_t bytes)->char*{
    char* p = ws + off; off = (off + bytes + 255) & ~(size_t)255; return p;
  };
  float* pA     = (float*)take(3844*4);
  float* palpha = (float*)take(72*4);
  float* pzz    = (float*)take(16384*4);
  u16*   pWhhH  = (u16*)take(12288*2);
  u16*   pM2    = (u16*)take((size_t)496*192*24*2);
  u16*   pU01   = (u16*)take((size_t)496*2048*24*2);
  float* pos    = (float*)take((size_t)126976*4);

  k_prep<<<1, 256, 0, stream>>>(E, Tp, Whh, bih, bhh, pA, palpha, pWhhH);
  k_m2<<<496, 256, 0, stream>>>(E, Wp, bp, Wih, bih, pM2);
  k_zz<<<512, 256, 0, stream>>>(PI, Wz, pzz);
  k_u<<<2048, 256, 0, stream>>>(x, pA, palpha, pzz, pU01);
  k_gru<<<3968, 256, 0, stream>>>(pU01, pM2, pWhhH, pos);
  k_mlp<<<256, 256, 0, stream>>>(pos, W1, b1, W2, b2, out);
}

// Round 6
// 204.847 us; speedup vs baseline: 3.1139x; 1.1352x over previous
//
#include <hip/hip_runtime.h>

typedef unsigned short u16;
typedef _Float16 f16;
typedef __attribute__((ext_vector_type(8))) _Float16 h8v;
typedef __attribute__((ext_vector_type(4))) float f4v;

#define SC_RZ (-1.44269504f)   // -1/ln2 : r,z gates -> sigm = rcp(1+exp2(acc))
#define SC_N  (2.88539008f)    //  2/ln2 : n gate    -> tanh = 1-2*rcp(1+exp2(acc))

__device__ __forceinline__ u16 f2h_bits(float f){
  f16 h = (f16)f;
  return __builtin_bit_cast(u16, h);
}
__device__ __forceinline__ float sigmf(float x){
  return __builtin_amdgcn_rcpf(1.f + __expf(-x));
}

// ---------------------------------------------------------------------------
// k_prepA: block n<62 -> A row n (wave softmax); block 62 -> alpha.
// ---------------------------------------------------------------------------
__global__ __launch_bounds__(64) void k_prepA(
    const float* __restrict__ E, const float* __restrict__ Tp,
    float* __restrict__ A, float* __restrict__ alpha)
{
  const int n = blockIdx.x, tid = threadIdx.x;
  if (n < 62){
    float e0 = E[n*3], e1 = E[n*3+1], e2 = E[n*3+2];
    float s = -1e30f;
    if (tid < 62){
      float d = e0*E[tid*3] + e1*E[tid*3+1] + e2*E[tid*3+2];
      s = d > 0.f ? d : 0.f;
    }
    float mx = s;
    #pragma unroll
    for (int off = 1; off < 64; off <<= 1) mx = fmaxf(mx, __shfl_xor(mx, off));
    float e = (tid < 62) ? __expf(s - mx) : 0.f;
    float sum = e;
    #pragma unroll
    for (int off = 1; off < 64; off <<= 1) sum += __shfl_xor(sum, off);
    if (tid < 62) A[n*62 + tid] = e / sum;
  } else {
    if (tid < 8){
      int t = tid;
      float mx = -1e30f;
      for (int s = 0; s <= t; ++s) mx = fmaxf(mx, Tp[t*9+s]);
      float sum = 0.f;
      for (int s = 0; s <= t; ++s) sum += __expf(Tp[t*9+s] - mx);
      float inv = 1.f / sum;
      for (int s = 0; s < 9; ++s)
        alpha[t*9+s] = (s <= t) ? __expf(Tp[t*9+s] - mx) * inv : 0.f;
    }
  }
}

// ---------------------------------------------------------------------------
// k_wpad: WhhH fp16 [3g][64 col][64 k], pre-scaled (SC_RZ / SC_N);
//         k=62 row carries gate biases (H[62]=1 homogeneous slot).
// ---------------------------------------------------------------------------
__global__ __launch_bounds__(256) void k_wpad(
    const float* __restrict__ Whh, const float* __restrict__ bih,
    const float* __restrict__ bhh, u16* __restrict__ WhhH)
{
  int i = blockIdx.x*256 + threadIdx.x;
  if (i >= 12288) return;
  int row = i >> 6, k = i & 63, g = row >> 6, jj = row & 63;
  float sc = (g == 2) ? SC_N : SC_RZ;
  float vh = 0.f;
  if (jj < 62){
    if (k < 62) vh = Whh[(g*62+jj)*62 + k];
    else if (k == 62) vh = (g < 2) ? (bih[g*62+jj] + bhh[g*62+jj]) : bhh[124+jj];
  }
  WhhH[i] = f2h_bits(vh * sc);
}

// ---------------------------------------------------------------------------
// k_m2: M2[((t*62+n)*192+col)*32 + k] fp16, pre-scaled. k<20 data,
//       k=20 -> biasW, k=21 -> b_ih(n gate), k=22..31 zero.
// ---------------------------------------------------------------------------
__global__ __launch_bounds__(256) void k_m2(
    const float* __restrict__ E, const float* __restrict__ Wp,
    const float* __restrict__ bp, const float* __restrict__ Wih,
    const float* __restrict__ bih, u16* __restrict__ M2)
{
  const int bid = blockIdx.x;          // t*62+n
  const int t = bid / 62, n = bid % 62, tid = threadIdx.x;
  __shared__ float w2s[1240];          // [o][k20]
  __shared__ float bias[62];
  const float e0 = E[n*3], e1 = E[n*3+1], e2 = E[n*3+2];
  for (int i = tid; i < 1240; i += 256){
    int o = i / 20, k = i % 20, c = k >> 1, kl = k & 1;
    w2s[i] = e0*Wp[(((t*3+0)*2+kl)*10+c)*62 + o]
           + e1*Wp[(((t*3+1)*2+kl)*10+c)*62 + o]
           + e2*Wp[(((t*3+2)*2+kl)*10+c)*62 + o];
  }
  if (tid < 62)
    bias[tid] = e0*bp[(t*3+0)*62+tid] + e1*bp[(t*3+1)*62+tid]
              + e2*bp[(t*3+2)*62+tid];
  __syncthreads();
  for (int i = tid; i < 3072; i += 256){   // 192 cols x 16 dwords
    int col = i >> 4, d = i & 15, g = col >> 6, jj = col & 63;
    float sc = (g == 2) ? SC_N : SC_RZ;
    unsigned outw = 0;
    if (jj < 62){
      const float* wr = Wih + (g*62+jj)*62;
      if (d < 10){
        int k0 = 2*d;
        float v0 = 0.f, v1 = 0.f;
        for (int o = 0; o < 62; ++o){
          float w = wr[o];
          v0 += w * w2s[o*20 + k0];
          v1 += w * w2s[o*20 + k0 + 1];
        }
        outw = (unsigned)f2h_bits(v0*sc) | ((unsigned)f2h_bits(v1*sc) << 16);
      } else if (d == 10){
        float v0 = 0.f;
        for (int o = 0; o < 62; ++o) v0 += wr[o]*bias[o];
        float v1 = (g == 2) ? bih[124+jj] : 0.f;
        outw = (unsigned)f2h_bits(v0*sc) | ((unsigned)f2h_bits(v1*sc) << 16);
      }
    }
    ((unsigned*)M2)[((size_t)bid*192 + col)*16 + d] = outw;
  }
}

// ---------------------------------------------------------------------------
// k_zz: 4 batches/block, float4; zz[t][b] = sigmoid(sum_p PI[b,p]*Wz[t,p])
// ---------------------------------------------------------------------------
__global__ __launch_bounds__(256) void k_zz(
    const float* __restrict__ PI, const float* __restrict__ Wz,
    float* __restrict__ zzO)
{
  const int b0 = blockIdx.x*4, tid = threadIdx.x;
  float acc[32];
  #pragma unroll
  for (int i = 0; i < 32; ++i) acc[i] = 0.f;
  const float4* p0 = (const float4*)(PI + (size_t)(b0+0)*10000);
  const float4* p1 = (const float4*)(PI + (size_t)(b0+1)*10000);
  const float4* p2 = (const float4*)(PI + (size_t)(b0+2)*10000);
  const float4* p3 = (const float4*)(PI + (size_t)(b0+3)*10000);
  const float4* wz4 = (const float4*)Wz;
  for (int p = tid; p < 2500; p += 256){
    float4 x0 = p0[p], x1 = p1[p], x2 = p2[p], x3 = p3[p];
    #pragma unroll
    for (int t = 0; t < 8; ++t){
      float4 w = wz4[t*2500 + p];
      acc[t*4+0] += x0.x*w.x + x0.y*w.y + x0.z*w.z + x0.w*w.w;
      acc[t*4+1] += x1.x*w.x + x1.y*w.y + x1.z*w.z + x1.w*w.w;
      acc[t*4+2] += x2.x*w.x + x2.y*w.y + x2.z*w.z + x2.w*w.w;
      acc[t*4+3] += x3.x*w.x + x3.y*w.y + x3.z*w.z + x3.w*w.w;
    }
  }
  __shared__ float red[128];
  int lane = tid & 63, wid = tid >> 6;
  #pragma unroll
  for (int i = 0; i < 32; ++i){
    float v = acc[i];
    v += __shfl_xor(v, 1);  v += __shfl_xor(v, 2);  v += __shfl_xor(v, 4);
    v += __shfl_xor(v, 8);  v += __shfl_xor(v, 16); v += __shfl_xor(v, 32);
    if (lane == 0) red[i*4 + wid] = v;
  }
  __syncthreads();
  if (tid < 32){
    float s = red[tid*4] + red[tid*4+1] + red[tid*4+2] + red[tid*4+3];
    int t = tid >> 2, bq = tid & 3;
    zzO[t*2048 + b0 + bq] = sigmf(s);
  }
}

// ---------------------------------------------------------------------------
// k_u: per batch b. A-mix via one 64x80x64 fp16 MFMA GEMM (xg = A @ [x_s,c]),
//      then combine pass writes U01[((t*62+n)*2048+b)*32 + k]:
//      k=2c+part (0=U0,1=U1), k=20 -> zz, k=21 -> 1.0, k=22..31 -> 0.
// ---------------------------------------------------------------------------
__global__ __launch_bounds__(256) void k_u(
    const float* __restrict__ x, const float* __restrict__ A,
    const float* __restrict__ alpha, const float* __restrict__ zz,
    u16* __restrict__ U01)
{
  const int b = blockIdx.x, tid = threadIdx.x;
  __shared__ float xs[5580];      // [s][m][c] fp32
  __shared__ f16 xT[80*72];       // [(s1*10+c)][m]  (B operand, k=m)
  __shared__ f16 A16[64*72];      // [n][m]          (A operand)
  __shared__ f16 xg[64*80];       // [n][(s1*10+c)]
  __shared__ float al[72];
  __shared__ float zzb[8];

  const float* pxb = x + (size_t)b*5580;
  const float4* px4 = (const float4*)pxb;
  for (int i = tid; i < 1395; i += 256) ((float4*)xs)[i] = px4[i];
  for (int i = tid; i < 3844; i += 256){
    int n = i / 62, m = i % 62;
    A16[n*72 + m] = (f16)A[i];
  }
  for (int i = tid; i < 640; i += 256) A16[(i/10)*72 + 62 + (i%10)] = (f16)0.f;
  for (int i = tid; i < 124; i += 256) A16[(62 + i/62)*72 + (i%62)] = (f16)0.f;
  for (int i = tid; i < 4960; i += 256){
    int s1 = i / 620, r = i % 620, m = r / 10, c = r % 10;
    xT[(s1*10 + c)*72 + m] = (f16)pxb[620 + i];
  }
  for (int i = tid; i < 800; i += 256) xT[(i/10)*72 + 62 + (i%10)] = (f16)0.f;
  if (tid < 72) al[tid] = alpha[tid];
  if (tid < 8) zzb[tid] = zz[tid*2048 + b];
  __syncthreads();

  // ---- MFMA: xg[n][ct] = sum_m A16[n][m] * xT[ct][m] ----
  {
    const int w_id = tid >> 6, lane = tid & 63, ln = lane & 15, hi = lane >> 4;
    h8v af0 = *(const h8v*)&A16[(w_id*16 + ln)*72 + hi*8];
    h8v af1 = *(const h8v*)&A16[(w_id*16 + ln)*72 + 32 + hi*8];
    f4v Z4 = {0.f, 0.f, 0.f, 0.f};
    #pragma unroll
    for (int Nt = 0; Nt < 5; ++Nt){
      h8v bf0 = *(const h8v*)&xT[(Nt*16 + ln)*72 + hi*8];
      h8v bf1 = *(const h8v*)&xT[(Nt*16 + ln)*72 + 32 + hi*8];
      f4v acc = __builtin_amdgcn_mfma_f32_16x16x32_f16(af0, bf0, Z4, 0,0,0);
      acc = __builtin_amdgcn_mfma_f32_16x16x32_f16(af1, bf1, acc, 0,0,0);
      #pragma unroll
      for (int rg = 0; rg < 4; ++rg)
        xg[(w_id*16 + hi*4 + rg)*80 + Nt*16 + ln] = (f16)acc[rg];
    }
  }
  __syncthreads();

  // ---- combine + packed writeout (K=32, zero-padded) ----
  const int t = tid >> 5, nq = (tid >> 1) & 15, ch = tid & 1;
  const int n0 = nq*4, c0 = ch*5;
  float alr[9];
  #pragma unroll
  for (int s = 0; s < 9; ++s) alr[s] = al[t*9+s];
  const float z = zzb[t];
  const unsigned zpack = (unsigned)f2h_bits(z) | (0x3C00u << 16);  // [zz|1.0]
  #pragma unroll
  for (int i = 0; i < 4; ++i){
    int n = n0 + i;
    if (n < 62){
      unsigned pk[5];
      #pragma unroll
      for (int c = 0; c < 5; ++c){
        int cc = c0 + c;
        float xw = 0.f;
        #pragma unroll
        for (int s = 0; s < 9; ++s) xw += alr[s]*xs[s*620 + n*10 + cc];
        float u0 = z*xs[(t+1)*620 + n*10 + cc] + xw;
        float u1 = z*(float)xg[n*80 + t*10 + cc];
        pk[c] = (unsigned)f2h_bits(u0) | ((unsigned)f2h_bits(u1) << 16);
      }
      unsigned* dst = (unsigned*)(U01 + ((size_t)(t*62 + n)*2048 + b)*32);
      #pragma unroll
      for (int c = 0; c < 5; ++c) dst[c0 + c] = pk[c];
      if (ch == 0){ dst[10] = zpack; dst[12] = 0; dst[13] = 0; }
      else        { dst[11] = 0;     dst[14] = 0; dst[15] = 0; }
    }
  }
}

// ---------------------------------------------------------------------------
// k_gru: pre-scaled, affine-folded GRU. One barrier/step; U+M2 prefetched a
// full step ahead; branchless K=32 fragments; zero-C first MFMA.
// Block = (n, 32-batch tile), 4 col-split waves.
// ---------------------------------------------------------------------------
__global__ __launch_bounds__(256, 3) void k_gru(
    const u16* __restrict__ U01, const u16* __restrict__ M2,
    const u16* __restrict__ WhhH, float* __restrict__ outSum)
{
  __shared__ f16 Hs[2][32*72];
  __shared__ float red[128];

  const int tid = threadIdx.x;
  int bid = blockIdx.x;
  bid = (bid & 7)*496 + (bid >> 3);     // XCD-bijective: same-n -> same XCD
  const int n_idx = bid >> 6;
  const int b0 = (bid & 63) << 5;
  const int lane = tid & 63;
  const int w_id = tid >> 6;
  const int ln = lane & 15;
  const int hi = lane >> 4;
  const int j = w_id*16 + ln;

  // persistent pre-scaled Whh B-fragments
  h8v whhF[3][2];
  #pragma unroll
  for (int g = 0; g < 3; ++g)
    #pragma unroll
    for (int ks = 0; ks < 2; ++ks)
      whhF[g][ks] = *(const h8v*)(const void*)(WhhH + (g*64 + j)*64 + ks*32 + hi*8);

  for (int i = tid; i < 2304; i += 256){
    f16 v = ((i % 72) == 62) ? (f16)1.f : (f16)0.f;
    Hs[0][i] = v; Hs[1][i] = v;
  }

  const u16* pU = U01 + ((size_t)n_idx*2048 + b0)*32;
  const u16* pM = M2 + (size_t)n_idx*192*32;
  const int oU0 = ln*32 + hi*8;
  const int oU1 = (16 + ln)*32 + hi*8;
  const int oM0 = j*32 + hi*8;
  const int oM1 = (64 + j)*32 + hi*8;
  const int oM2 = (128 + j)*32 + hi*8;
  const size_t TSU = (size_t)62*2048*32;
  const size_t TSM = (size_t)62*192*32;

  h8v uA0 = *(const h8v*)(const void*)(pU + oU0);
  h8v uA1 = *(const h8v*)(const void*)(pU + oU1);
  h8v mA0 = *(const h8v*)(const void*)(pM + oM0);
  h8v mA1 = *(const h8v*)(const void*)(pM + oM1);
  h8v mA2 = *(const h8v*)(const void*)(pM + oM2);
  h8v uB0, uB1, mB0, mB1, mB2;

  float h_reg[8];
  #pragma unroll
  for (int i = 0; i < 8; ++i) h_reg[i] = 0.f;
  __syncthreads();

  const f4v Z4 = {0.f, 0.f, 0.f, 0.f};
  #pragma unroll
  for (int t = 0; t < 8; ++t){
    const int p = t & 1;
    if (t < 7){
      const u16* qU = pU + (size_t)(t+1)*TSU;
      const u16* qM = pM + (size_t)(t+1)*TSM;
      uB0 = *(const h8v*)(const void*)(qU + oU0);
      uB1 = *(const h8v*)(const void*)(qU + oU1);
      mB0 = *(const h8v*)(const void*)(qM + oM0);
      mB1 = *(const h8v*)(const void*)(qM + oM1);
      mB2 = *(const h8v*)(const void*)(qM + oM2);
    }
    h8v hf00 = *(const h8v*)&Hs[p][ln*72 + hi*8];
    h8v hf01 = *(const h8v*)&Hs[p][ln*72 + 32 + hi*8];
    h8v hf10 = *(const h8v*)&Hs[p][(16+ln)*72 + hi*8];
    h8v hf11 = *(const h8v*)&Hs[p][(16+ln)*72 + 32 + hi*8];

    f4v ar[2], az[2], axn[2], ahn[2];
    ar[0]  = __builtin_amdgcn_mfma_f32_16x16x32_f16(hf00, whhF[0][0], Z4, 0,0,0);
    ar[0]  = __builtin_amdgcn_mfma_f32_16x16x32_f16(hf01, whhF[0][1], ar[0], 0,0,0);
    ar[0]  = __builtin_amdgcn_mfma_f32_16x16x32_f16(uA0, mA0, ar[0], 0,0,0);
    ar[1]  = __builtin_amdgcn_mfma_f32_16x16x32_f16(hf10, whhF[0][0], Z4, 0,0,0);
    ar[1]  = __builtin_amdgcn_mfma_f32_16x16x32_f16(hf11, whhF[0][1], ar[1], 0,0,0);
    ar[1]  = __builtin_amdgcn_mfma_f32_16x16x32_f16(uA1, mA0, ar[1], 0,0,0);
    az[0]  = __builtin_amdgcn_mfma_f32_16x16x32_f16(hf00, whhF[1][0], Z4, 0,0,0);
    az[0]  = __builtin_amdgcn_mfma_f32_16x16x32_f16(hf01, whhF[1][1], az[0], 0,0,0);
    az[0]  = __builtin_amdgcn_mfma_f32_16x16x32_f16(uA0, mA1, az[0], 0,0,0);
    az[1]  = __builtin_amdgcn_mfma_f32_16x16x32_f16(hf10, whhF[1][0], Z4, 0,0,0);
    az[1]  = __builtin_amdgcn_mfma_f32_16x16x32_f16(hf11, whhF[1][1], az[1], 0,0,0);
    az[1]  = __builtin_amdgcn_mfma_f32_16x16x32_f16(uA1, mA1, az[1], 0,0,0);
    ahn[0] = __builtin_amdgcn_mfma_f32_16x16x32_f16(hf00, whhF[2][0], Z4, 0,0,0);
    ahn[0] = __builtin_amdgcn_mfma_f32_16x16x32_f16(hf01, whhF[2][1], ahn[0], 0,0,0);
    ahn[1] = __builtin_amdgcn_mfma_f32_16x16x32_f16(hf10, whhF[2][0], Z4, 0,0,0);
    ahn[1] = __builtin_amdgcn_mfma_f32_16x16x32_f16(hf11, whhF[2][1], ahn[1], 0,0,0);
    axn[0] = __builtin_amdgcn_mfma_f32_16x16x32_f16(uA0, mA2, Z4, 0,0,0);
    axn[1] = __builtin_amdgcn_mfma_f32_16x16x32_f16(uA1, mA2, Z4, 0,0,0);

    const bool last = (t == 7);
    #pragma unroll
    for (int mi = 0; mi < 2; ++mi)
      #pragma unroll
      for (int rg = 0; rg < 4; ++rg){
        float r  = __builtin_amdgcn_rcpf(1.f + exp2f(ar[mi][rg]));
        float zg = __builtin_amdgcn_rcpf(1.f + exp2f(az[mi][rg]));
        float yn = axn[mi][rg] + r*ahn[mi][rg];
        float ng = fmaf(-2.f, __builtin_amdgcn_rcpf(1.f + exp2f(yn)), 1.f);
        int idx = mi*4 + rg;
        float hnew = ng + zg*(h_reg[idx] - ng);
        h_reg[idx] = hnew;
        if (!last && j < 62)
          Hs[p^1][(mi*16 + hi*4 + rg)*72 + j] = (f16)hnew;
      }
    uA0 = uB0; uA1 = uB1; mA0 = mB0; mA1 = mB1; mA2 = mB2;
    __syncthreads();
  }

  // ---- row-sum over hidden dim (mask pad cols 62,63) ----
  #pragma unroll
  for (int mi = 0; mi < 2; ++mi)
    #pragma unroll
    for (int rg = 0; rg < 4; ++rg){
      float v = (j < 62) ? h_reg[mi*4 + rg] : 0.f;
      v += __shfl_xor(v, 1); v += __shfl_xor(v, 2);
      v += __shfl_xor(v, 4); v += __shfl_xor(v, 8);
      if (ln == 0) red[w_id*32 + mi*16 + hi*4 + rg] = v;
    }
  __syncthreads();
  if (tid < 32)
    outSum[(size_t)n_idx*2048 + b0 + tid] =
        red[tid] + red[32+tid] + red[64+tid] + red[96+tid];
}

// ---------------------------------------------------------------------------
// k_mlp: 8 batches per block; W1 staged in LDS.
// ---------------------------------------------------------------------------
__global__ __launch_bounds__(256) void k_mlp(
    const float* __restrict__ outSum,
    const float* __restrict__ W1, const float* __restrict__ b1,
    const float* __restrict__ W2, const float* __restrict__ b2,
    float* __restrict__ out)
{
  const int b0 = blockIdx.x*8, tid = threadIdx.x;
  __shared__ float W1s[15872];    // 256 x 62
  __shared__ float vec[8][62];
  __shared__ float o1[8][256];
  for (int i = tid; i < 15872; i += 256) W1s[i] = W1[i];
  for (int i = tid; i < 496; i += 256){
    int n = i >> 3, bl = i & 7;
    vec[bl][n] = outSum[(size_t)n*2048 + b0 + bl];
  }
  __syncthreads();
  {
    float a[8];
    #pragma unroll
    for (int bl = 0; bl < 8; ++bl) a[bl] = b1[tid];
    for (int n = 0; n < 62; ++n){
      float w = W1s[tid*62 + n];
      #pragma unroll
      for (int bl = 0; bl < 8; ++bl) a[bl] += w * vec[bl][n];
    }
    #pragma unroll
    for (int bl = 0; bl < 8; ++bl) o1[bl][tid] = fmaxf(a[bl], 0.f);
  }
  __syncthreads();
  if (tid < 24){
    int bl = tid / 3, o = tid % 3;
    float s = b2[o];
    for (int k = 0; k < 256; ++k) s += o1[bl][k]*W2[o*256 + k];
    out[(b0+bl)*3 + o] = fmaxf(s, 0.f);
  }
}

// ---------------------------------------------------------------------------
extern "C" void kernel_launch(void* const* d_in, const int* in_sizes, int n_in,
                              void* d_out, int out_size, void* d_ws, size_t ws_size,
                              hipStream_t stream)
{
  const float* x   = (const float*)d_in[0];
  const float* PI  = (const float*)d_in[1];
  const float* E   = (const float*)d_in[2];
  const float* Wp  = (const float*)d_in[3];
  const float* bp  = (const float*)d_in[4];
  const float* Tp  = (const float*)d_in[5];
  const float* Wz  = (const float*)d_in[6];
  const float* Wih = (const float*)d_in[7];
  const float* Whh = (const float*)d_in[8];
  const float* bih = (const float*)d_in[9];
  const float* bhh = (const float*)d_in[10];
  const float* W1  = (const float*)d_in[11];
  const float* b1  = (const float*)d_in[12];
  const float* W2  = (const float*)d_in[13];
  const float* b2  = (const float*)d_in[14];
  float* out = (float*)d_out;

  char* ws = (char*)d_ws;
  size_t off = 0;
  auto take = [&](size_t bytes)->char*{
    char* p = ws + off; off = (off + bytes + 255) & ~(size_t)255; return p;
  };
  float* pA     = (float*)take(3844*4);
  float* palpha = (float*)take(72*4);
  float* pzz    = (float*)take(16384*4);
  u16*   pWhhH  = (u16*)take(12288*2);
  u16*   pM2    = (u16*)take((size_t)496*192*32*2);
  u16*   pU01   = (u16*)take((size_t)496*2048*32*2);
  float* pos    = (float*)take((size_t)126976*4);

  k_prepA<<<63, 64, 0, stream>>>(E, Tp, pA, palpha);
  k_wpad<<<48, 256, 0, stream>>>(Whh, bih, bhh, pWhhH);
  k_m2<<<496, 256, 0, stream>>>(E, Wp, bp, Wih, bih, pM2);
  k_zz<<<512, 256, 0, stream>>>(PI, Wz, pzz);
  k_u<<<2048, 256, 0, stream>>>(x, pA, palpha, pzz, pU01);
  k_gru<<<3968, 256, 0, stream>>>(pU01, pM2, pWhhH, pos);
  k_mlp<<<256, 256, 0, stream>>>(pos, W1, b1, W2, b2, out);
}